// Round 7
// baseline (2048.386 us; speedup 1.0000x reference)
//
#include <hip/hip_runtime.h>

#define N_NODES 50000
#define N_EDGES 800000
#define NUM_GRAPHS 16
#define NUM_CLASSES 247
#define SCAN_BLOCKS ((N_NODES + 255) / 256)  // 196

static inline int nblk(long n) { return (int)((n + 255) / 256); }

// ---- degree histogram (int) ------------------------------------------------
__global__ void k_deg(const int* __restrict__ col, int* __restrict__ degi, int E) {
    int e = blockIdx.x * blockDim.x + threadIdx.x;
    if (e < E) atomicAdd(&degi[col[e]], 1);
}

// ---- hierarchical exclusive scan + batch histogram (fused) -----------------
__global__ __launch_bounds__(256) void k_scan1(const int* __restrict__ degi,
                                               int* __restrict__ rowptr,
                                               int* __restrict__ bsum,
                                               const int* __restrict__ batch,
                                               float* __restrict__ pcnt, int N) {
    __shared__ int buf[256];
    __shared__ int hist[NUM_GRAPHS];
    int t = threadIdx.x;
    if (t < NUM_GRAPHS) hist[t] = 0;
    int i = blockIdx.x * 256 + t;
    int v = (i < N) ? degi[i] : 0;
    buf[t] = v;
    if (i < N) atomicAdd(&hist[batch[i]], 1);
    __syncthreads();
#pragma unroll
    for (int off = 1; off < 256; off <<= 1) {
        int tmp = (t >= off) ? buf[t - off] : 0;
        __syncthreads();
        if (t >= off) buf[t] += tmp;
        __syncthreads();
    }
    if (i < N) rowptr[i] = buf[t] - v;  // exclusive within block
    if (t == 255) bsum[blockIdx.x] = buf[255];
    if (t < NUM_GRAPHS && hist[t] > 0) atomicAdd(&pcnt[t], (float)hist[t]);
}

__global__ __launch_bounds__(256) void k_scan2(int* __restrict__ bsum, int nb) {
    __shared__ int buf[256];
    int t = threadIdx.x;
    int v = (t < nb) ? bsum[t] : 0;
    buf[t] = v;
    __syncthreads();
#pragma unroll
    for (int off = 1; off < 256; off <<= 1) {
        int tmp = (t >= off) ? buf[t - off] : 0;
        __syncthreads();
        if (t >= off) buf[t] += tmp;
        __syncthreads();
    }
    if (t < nb) bsum[t] = buf[t] - v;  // exclusive
}

// phase 3: add block offsets; also compute dinv
__global__ __launch_bounds__(256) void k_scan3(int* __restrict__ rowptr,
                                               const int* __restrict__ bsum,
                                               const int* __restrict__ degi,
                                               float* __restrict__ dinv, int N) {
    int i = blockIdx.x * 256 + (int)threadIdx.x;
    if (i < N) {
        rowptr[i] += bsum[blockIdx.x];
        dinv[i] = rsqrtf((float)degi[i] + 1.0f);  // +1 = self loop
    }
    if (i == 0) rowptr[N] = N_EDGES;
}

// ---- CSR fill: csr_src[rowptr[c] + pos] = r (nontemporal scatter) ----------
__global__ void k_fill(const int* __restrict__ row, const int* __restrict__ col,
                       const int* __restrict__ rowptr, int* __restrict__ cursor,
                       int* __restrict__ csr_src, int E) {
    int e = blockIdx.x * blockDim.x + threadIdx.x;
    if (e >= E) return;
    int c = col[e];
    int pos = atomicAdd(&cursor[c], 1);
    __builtin_nontemporal_store(row[e], &csr_src[rowptr[c] + pos]);
}

// ---- propagation, F=3 (raw x), thread per node -----------------------------
__global__ void k_prop3(const float* __restrict__ x, const float* __restrict__ dinv,
                        const int* __restrict__ rowptr, const int* __restrict__ csr_src,
                        float* __restrict__ out, int N) {
    int v = blockIdx.x * blockDim.x + threadIdx.x;
    if (v >= N) return;
    float dv = dinv[v];
    float a0 = dv * x[v * 3 + 0];
    float a1 = dv * x[v * 3 + 1];
    float a2 = dv * x[v * 3 + 2];
    int j1 = rowptr[v + 1];
    for (int j = rowptr[v]; j < j1; ++j) {
        int r = csr_src[j];
        float dr = dinv[r];
        a0 += dr * x[r * 3 + 0];
        a1 += dr * x[r * 3 + 1];
        a2 += dr * x[r * 3 + 2];
    }
    out[v * 3 + 0] = dv * a0;
    out[v * 3 + 1] = dv * a1;
    out[v * 3 + 2] = dv * a2;
}

// ---- propagation, F in {64,128}: wave per node, 8-edge unroll --------------
template <int F>
__global__ __launch_bounds__(256) void k_prop(
        const float* __restrict__ h, const float* __restrict__ dinv,
        const int* __restrict__ rowptr, const int* __restrict__ csr_src,
        float* __restrict__ out, int N) {
    constexpr int K = F / 64;  // contiguous floats per lane (1 or 2)
    int wave = threadIdx.x >> 6;
    int lane = threadIdx.x & 63;
    int v = blockIdx.x * 4 + wave;
    if (v >= N) return;
    float dv = dinv[v];
    float acc[K];
    const float* hv = h + (long)v * F + lane * K;
#pragma unroll
    for (int k = 0; k < K; ++k) acc[k] = dv * hv[k];
    int j0 = __builtin_amdgcn_readfirstlane(rowptr[v]);
    int j1 = __builtin_amdgcn_readfirstlane(rowptr[v + 1]);
    int j = j0;
    for (; j + 8 <= j1; j += 8) {
        int r[8];
        float d[8];
        const float* hp[8];
#pragma unroll
        for (int u = 0; u < 8; ++u) r[u] = csr_src[j + u];
#pragma unroll
        for (int u = 0; u < 8; ++u) d[u] = dinv[r[u]];
#pragma unroll
        for (int u = 0; u < 8; ++u) hp[u] = h + (long)r[u] * F + lane * K;
        float t[8][K];
#pragma unroll
        for (int u = 0; u < 8; ++u)
#pragma unroll
            for (int k = 0; k < K; ++k) t[u][k] = hp[u][k];
#pragma unroll
        for (int u = 0; u < 8; ++u)
#pragma unroll
            for (int k = 0; k < K; ++k) acc[k] = fmaf(d[u], t[u][k], acc[k]);
    }
    for (; j + 4 <= j1; j += 4) {
        int r0 = csr_src[j + 0], r1 = csr_src[j + 1];
        int r2 = csr_src[j + 2], r3 = csr_src[j + 3];
        float d0 = dinv[r0], d1 = dinv[r1], d2 = dinv[r2], d3 = dinv[r3];
        const float* h0 = h + (long)r0 * F + lane * K;
        const float* h1 = h + (long)r1 * F + lane * K;
        const float* h2 = h + (long)r2 * F + lane * K;
        const float* h3 = h + (long)r3 * F + lane * K;
#pragma unroll
        for (int k = 0; k < K; ++k) {
            float t0 = h0[k], t1 = h1[k], t2 = h2[k], t3 = h3[k];
            acc[k] = fmaf(d0, t0, acc[k]);
            acc[k] = fmaf(d1, t1, acc[k]);
            acc[k] = fmaf(d2, t2, acc[k]);
            acc[k] = fmaf(d3, t3, acc[k]);
        }
    }
    for (; j < j1; ++j) {
        int r = csr_src[j];
        float dr = dinv[r];
        const float* hr = h + (long)r * F + lane * K;
#pragma unroll
        for (int k = 0; k < K; ++k) acc[k] = fmaf(dr, hr[k], acc[k]);
    }
    float* ov = out + (long)v * F + lane * K;
#pragma unroll
    for (int k = 0; k < K; ++k) ov[k] = dv * acc[k];
}

// ---- naive linear for tiny FIN=3 layer -------------------------------------
__global__ void k_lin3(const float* __restrict__ h, const float* __restrict__ W,
                       const float* __restrict__ b, float* __restrict__ out, int N) {
    long tid = (long)blockIdx.x * blockDim.x + threadIdx.x;
    if (tid >= (long)N * 64) return;
    int v = (int)(tid / 64);
    int f = (int)(tid % 64);
    const float* hr = h + (long)v * 3;
    float s = b[f];
    s = fmaf(hr[0], W[0 * 64 + f], s);
    s = fmaf(hr[1], W[1 * 64 + f], s);
    s = fmaf(hr[2], W[2 * 64 + f], s);
    out[tid] = s > 0.0f ? s : 0.0f;
}

// ---- LDS-staged GEMM: W k-chunks in LDS, zero global loads in inner loop ---
// TILE=32 nodes/block. Threads: FG=FOUT/4 f-groups x VG v-groups.
// W chunk [KC][FOUT] staged cooperatively (coalesced float4), read back as
// lane-strided b128 (conflict-free); h tile read as wave-broadcast b128.
// FMA order: k ascending -> bit-identical to previous rounds.
template <int FIN, int FOUT, int KC, bool RELU>
__global__ __launch_bounds__(256) void k_gemm(
        const float* __restrict__ h, const float* __restrict__ W,
        const float* __restrict__ b, float* __restrict__ out, int N) {
    constexpr int TILE = 32;
    constexpr int FG = FOUT / 4;    // 64 (FOUT=256) / 32 (FOUT=128)
    constexpr int VG = 256 / FG;    // 4 / 8
    constexpr int VPT = TILE / VG;  // 8 / 4
    constexpr int ROWF4 = FIN / 4;
    __shared__ float hs[TILE][FIN];   // 16 KB / 8 KB
    __shared__ float ws[KC * FOUT];   // 16 KB
    int t = threadIdx.x;
    int fg = t % FG;
    int vg = t / FG;
    int v0 = blockIdx.x * TILE;
    // stage h tile (fenced by first chunk's leading barrier)
    for (int i = t; i < TILE * ROWF4; i += 256) {
        int vv = i / ROWF4, kk = i % ROWF4;
        int vsrc = v0 + vv;
        if (vsrc >= N) vsrc = N - 1;  // tail clamp; stores guarded
        *(float4*)&hs[vv][kk * 4] = ((const float4*)(h + (long)vsrc * FIN))[kk];
    }
    float4 bias = ((const float4*)b)[fg];
    float acc[VPT][4];
#pragma unroll
    for (int i = 0; i < VPT; ++i) {
        acc[i][0] = bias.x; acc[i][1] = bias.y;
        acc[i][2] = bias.z; acc[i][3] = bias.w;
    }
    for (int kc = 0; kc < FIN; kc += KC) {
        __syncthreads();  // ws free (and, first iter, h staged)
        // stage W chunk: rows kc..kc+KC are contiguous in W
        const float4* Wsrc = (const float4*)(W + (long)kc * FOUT);
#pragma unroll
        for (int i = t; i < KC * FOUT / 4; i += 256)
            ((float4*)ws)[i] = Wsrc[i];
        __syncthreads();
#pragma unroll
        for (int kk = 0; kk < KC; kk += 4) {
            float4 hv[VPT];
#pragma unroll
            for (int i = 0; i < VPT; ++i)
                hv[i] = *(const float4*)&hs[vg * VPT + i][kc + kk];
#pragma unroll
            for (int j = 0; j < 4; ++j) {
                float4 w = *(const float4*)&ws[(kk + j) * FOUT + fg * 4];
#pragma unroll
                for (int i = 0; i < VPT; ++i) {
                    float hvv = (j == 0) ? hv[i].x : (j == 1) ? hv[i].y
                              : (j == 2) ? hv[i].z : hv[i].w;
                    acc[i][0] = fmaf(hvv, w.x, acc[i][0]);
                    acc[i][1] = fmaf(hvv, w.y, acc[i][1]);
                    acc[i][2] = fmaf(hvv, w.z, acc[i][2]);
                    acc[i][3] = fmaf(hvv, w.w, acc[i][3]);
                }
            }
        }
    }
#pragma unroll
    for (int i = 0; i < VPT; ++i) {
        int v = v0 + vg * VPT + i;
        if (v < N) {
            float4 r;
            r.x = RELU ? fmaxf(acc[i][0], 0.0f) : acc[i][0];
            r.y = RELU ? fmaxf(acc[i][1], 0.0f) : acc[i][1];
            r.z = RELU ? fmaxf(acc[i][2], 0.0f) : acc[i][2];
            r.w = RELU ? fmaxf(acc[i][3], 0.0f) : acc[i][3];
            ((float4*)(out + (long)v * FOUT))[fg] = r;
        }
    }
}

// ---- pooling: 64 nodes/block, register accumulator, flush on graph change --
#define POOL_CHUNK 64
__global__ __launch_bounds__(256) void k_pool(
        const float* __restrict__ h, const int* __restrict__ batch,
        float* __restrict__ psum, int N) {
    int tid = threadIdx.x;  // feature
    int n0 = blockIdx.x * POOL_CHUNK;
    int n1 = n0 + POOL_CHUNK;
    if (n1 > N) n1 = N;
    int gcur = batch[n0];  // sorted -> uniform scalar
    float racc = 0.0f;
    for (int n = n0; n < n1; ++n) {
        int g = batch[n];
        if (g != gcur) {
            atomicAdd(&psum[gcur * 256 + tid], racc);
            racc = 0.0f;
            gcur = g;
        }
        racc += h[(long)n * 256 + tid];
    }
    atomicAdd(&psum[gcur * 256 + tid], racc);
}

// ---- final FC --------------------------------------------------------------
__global__ void k_fc(const float* __restrict__ psum, const float* __restrict__ pcnt,
                     const float* __restrict__ Wfc, const float* __restrict__ bfc,
                     float* __restrict__ out) {
    int tid = blockIdx.x * blockDim.x + threadIdx.x;
    if (tid >= NUM_GRAPHS * NUM_CLASSES) return;
    int g = tid / NUM_CLASSES;
    int c = tid % NUM_CLASSES;
    float s = 0.0f;
#pragma unroll 8
    for (int k = 0; k < 256; ++k) s = fmaf(psum[g * 256 + k], Wfc[k * NUM_CLASSES + c], s);
    float cnt = pcnt[g];
    cnt = cnt > 1.0f ? cnt : 1.0f;
    out[tid] = s / cnt + bfc[c];
}

extern "C" void kernel_launch(void* const* d_in, const int* in_sizes, int n_in,
                              void* d_out, int out_size, void* d_ws, size_t ws_size,
                              hipStream_t stream) {
    const float* x     = (const float*)d_in[0];
    const int*   ei    = (const int*)d_in[1];
    const int*   batch = (const int*)d_in[2];
    const float* W1    = (const float*)d_in[3];
    const float* b1    = (const float*)d_in[4];
    const float* W2    = (const float*)d_in[5];
    const float* b2    = (const float*)d_in[6];
    const float* W3    = (const float*)d_in[7];
    const float* b3    = (const float*)d_in[8];
    const float* Wfc   = (const float*)d_in[9];
    const float* bfc   = (const float*)d_in[10];
    float* out = (float*)d_out;

    const int* row = ei;            // src
    const int* col = ei + N_EDGES;  // dst

    // workspace layout (~81 MB); degi+cursor adjacent -> single memset
    float* bufA   = (float*)d_ws;                        // N*256
    float* bufB   = bufA + (size_t)N_NODES * 256;        // N*128
    float* dinv   = bufB + (size_t)N_NODES * 128;        // N
    float* psum   = dinv + N_NODES;                      // 16*256
    float* pcnt   = psum + NUM_GRAPHS * 256;             // 16
    int*   degi   = (int*)(pcnt + NUM_GRAPHS);           // N
    int*   cursor = degi + N_NODES;                      // N (adjacent to degi)
    int*   rowptr = cursor + N_NODES;                    // N+1
    int*   csrsrc = rowptr + N_NODES + 1;                // E
    int*   bsum   = csrsrc + N_EDGES;                    // SCAN_BLOCKS

    hipMemsetAsync(degi, 0, 2 * N_NODES * sizeof(int), stream);  // degi + cursor
    hipMemsetAsync(psum, 0, (NUM_GRAPHS * 256 + NUM_GRAPHS) * sizeof(float), stream);

    // ---- CSR build + norms (+ batch histogram fused into scan1) ----
    k_deg<<<nblk(N_EDGES), 256, 0, stream>>>(col, degi, N_EDGES);
    k_scan1<<<SCAN_BLOCKS, 256, 0, stream>>>(degi, rowptr, bsum, batch, pcnt, N_NODES);
    k_scan2<<<1, 256, 0, stream>>>(bsum, SCAN_BLOCKS);
    k_scan3<<<SCAN_BLOCKS, 256, 0, stream>>>(rowptr, bsum, degi, dinv, N_NODES);
    k_fill<<<nblk(N_EDGES), 256, 0, stream>>>(row, col, rowptr, cursor, csrsrc, N_EDGES);

    int prop_blocks = (N_NODES + 3) / 4;   // 4 nodes (waves) per block
    int gemm_blocks = (N_NODES + 31) / 32; // 32-node tiles

    // ---- layer 1: p1 = A~ x [N,3]; h1 = relu(p1 W1 + b1) [N,64] ----
    k_prop3<<<nblk(N_NODES), 256, 0, stream>>>(x, dinv, rowptr, csrsrc, bufB, N_NODES);
    k_lin3<<<nblk((long)N_NODES * 64), 256, 0, stream>>>(bufB, W1, b1, bufA, N_NODES);

    // ---- layer 2: p2 = A~ h1 [N,64]; h2 = relu(p2 W2 + b2) [N,128] ----
    k_prop<64><<<prop_blocks, 256, 0, stream>>>(bufA, dinv, rowptr, csrsrc, bufB, N_NODES);
    k_gemm<64, 128, 32, true><<<gemm_blocks, 256, 0, stream>>>(bufB, W2, b2, bufA, N_NODES);

    // ---- layer 3: p3 = A~ h2 [N,128]; h3 = relu(p3 W3 + b3) [N,256] ----
    k_prop<128><<<prop_blocks, 256, 0, stream>>>(bufA, dinv, rowptr, csrsrc, bufB, N_NODES);
    k_gemm<128, 256, 16, true><<<gemm_blocks, 256, 0, stream>>>(bufB, W3, b3, bufA, N_NODES);

    // ---- global mean pool + FC ----
    int pool_blocks = (N_NODES + POOL_CHUNK - 1) / POOL_CHUNK;
    k_pool<<<pool_blocks, 256, 0, stream>>>(bufA, batch, psum, N_NODES);
    k_fc<<<nblk(NUM_GRAPHS * NUM_CLASSES), 256, 0, stream>>>(psum, pcnt, Wfc, bfc, out);
}

// Round 8
// 366.530 us; speedup vs baseline: 5.5886x; 5.5886x over previous
//
#include <hip/hip_runtime.h>

#define N_NODES 50000
#define N_EDGES 800000
#define NUM_GRAPHS 16
#define NUM_CLASSES 247
#define SCAN_BLOCKS ((N_NODES + 255) / 256)  // 196

static inline int nblk(long n) { return (int)((n + 255) / 256); }

// ---- degree histogram; atomic return value = edge rank within dst ----------
__global__ void k_deg(const int* __restrict__ col, int* __restrict__ degi,
                      int* __restrict__ pos, int E) {
    int e = blockIdx.x * blockDim.x + threadIdx.x;
    if (e < E) pos[e] = atomicAdd(&degi[col[e]], 1);
}

// ---- hierarchical exclusive scan + batch histogram (fused) -----------------
__global__ __launch_bounds__(256) void k_scan1(const int* __restrict__ degi,
                                               int* __restrict__ rowptr,
                                               int* __restrict__ bsum,
                                               const int* __restrict__ batch,
                                               float* __restrict__ pcnt, int N) {
    __shared__ int buf[256];
    __shared__ int hist[NUM_GRAPHS];
    int t = threadIdx.x;
    if (t < NUM_GRAPHS) hist[t] = 0;
    int i = blockIdx.x * 256 + t;
    int v = (i < N) ? degi[i] : 0;
    buf[t] = v;
    if (i < N) atomicAdd(&hist[batch[i]], 1);
    __syncthreads();
#pragma unroll
    for (int off = 1; off < 256; off <<= 1) {
        int tmp = (t >= off) ? buf[t - off] : 0;
        __syncthreads();
        if (t >= off) buf[t] += tmp;
        __syncthreads();
    }
    if (i < N) rowptr[i] = buf[t] - v;  // exclusive within block
    if (t == 255) bsum[blockIdx.x] = buf[255];
    if (t < NUM_GRAPHS && hist[t] > 0) atomicAdd(&pcnt[t], (float)hist[t]);
}

__global__ __launch_bounds__(256) void k_scan2(int* __restrict__ bsum, int nb) {
    __shared__ int buf[256];
    int t = threadIdx.x;
    int v = (t < nb) ? bsum[t] : 0;
    buf[t] = v;
    __syncthreads();
#pragma unroll
    for (int off = 1; off < 256; off <<= 1) {
        int tmp = (t >= off) ? buf[t - off] : 0;
        __syncthreads();
        if (t >= off) buf[t] += tmp;
        __syncthreads();
    }
    if (t < nb) bsum[t] = buf[t] - v;  // exclusive
}

// phase 3: add block offsets; also compute dinv
__global__ __launch_bounds__(256) void k_scan3(int* __restrict__ rowptr,
                                               const int* __restrict__ bsum,
                                               const int* __restrict__ degi,
                                               float* __restrict__ dinv, int N) {
    int i = blockIdx.x * 256 + (int)threadIdx.x;
    if (i < N) {
        rowptr[i] += bsum[blockIdx.x];
        dinv[i] = rsqrtf((float)degi[i] + 1.0f);  // +1 = self loop
    }
    if (i == 0) rowptr[N] = N_EDGES;
}

// ---- CSR fill: no atomic — rank precomputed in k_deg -----------------------
__global__ void k_fill(const int* __restrict__ row, const int* __restrict__ col,
                       const int* __restrict__ rowptr, const int* __restrict__ pos,
                       int* __restrict__ csr_src, int E) {
    int e = blockIdx.x * blockDim.x + threadIdx.x;
    if (e >= E) return;
    int c = col[e];
    __builtin_nontemporal_store(row[e], &csr_src[rowptr[c] + pos[e]]);
}

// ---- propagation, F=3 (raw x), thread per node -----------------------------
__global__ void k_prop3(const float* __restrict__ x, const float* __restrict__ dinv,
                        const int* __restrict__ rowptr, const int* __restrict__ csr_src,
                        float* __restrict__ out, int N) {
    int v = blockIdx.x * blockDim.x + threadIdx.x;
    if (v >= N) return;
    float dv = dinv[v];
    float a0 = dv * x[v * 3 + 0];
    float a1 = dv * x[v * 3 + 1];
    float a2 = dv * x[v * 3 + 2];
    int j1 = rowptr[v + 1];
    for (int j = rowptr[v]; j < j1; ++j) {
        int r = csr_src[j];
        float dr = dinv[r];
        a0 += dr * x[r * 3 + 0];
        a1 += dr * x[r * 3 + 1];
        a2 += dr * x[r * 3 + 2];
    }
    out[v * 3 + 0] = dv * a0;
    out[v * 3 + 1] = dv * a1;
    out[v * 3 + 2] = dv * a2;
}

// ---- propagation, F in {64,128}: wave per node, 8-edge unroll --------------
template <int F>
__global__ __launch_bounds__(256) void k_prop(
        const float* __restrict__ h, const float* __restrict__ dinv,
        const int* __restrict__ rowptr, const int* __restrict__ csr_src,
        float* __restrict__ out, int N) {
    constexpr int K = F / 64;  // contiguous floats per lane (1 or 2)
    int wave = threadIdx.x >> 6;
    int lane = threadIdx.x & 63;
    int v = blockIdx.x * 4 + wave;
    if (v >= N) return;
    float dv = dinv[v];
    float acc[K];
    const float* hv = h + (long)v * F + lane * K;
#pragma unroll
    for (int k = 0; k < K; ++k) acc[k] = dv * hv[k];
    int j0 = __builtin_amdgcn_readfirstlane(rowptr[v]);
    int j1 = __builtin_amdgcn_readfirstlane(rowptr[v + 1]);
    int j = j0;
    for (; j + 8 <= j1; j += 8) {
        int r[8];
        float d[8];
        const float* hp[8];
#pragma unroll
        for (int u = 0; u < 8; ++u) r[u] = csr_src[j + u];
#pragma unroll
        for (int u = 0; u < 8; ++u) d[u] = dinv[r[u]];
#pragma unroll
        for (int u = 0; u < 8; ++u) hp[u] = h + (long)r[u] * F + lane * K;
        float t[8][K];
#pragma unroll
        for (int u = 0; u < 8; ++u)
#pragma unroll
            for (int k = 0; k < K; ++k) t[u][k] = hp[u][k];
#pragma unroll
        for (int u = 0; u < 8; ++u)
#pragma unroll
            for (int k = 0; k < K; ++k) acc[k] = fmaf(d[u], t[u][k], acc[k]);
    }
    for (; j + 4 <= j1; j += 4) {
        int r0 = csr_src[j + 0], r1 = csr_src[j + 1];
        int r2 = csr_src[j + 2], r3 = csr_src[j + 3];
        float d0 = dinv[r0], d1 = dinv[r1], d2 = dinv[r2], d3 = dinv[r3];
        const float* h0 = h + (long)r0 * F + lane * K;
        const float* h1 = h + (long)r1 * F + lane * K;
        const float* h2 = h + (long)r2 * F + lane * K;
        const float* h3 = h + (long)r3 * F + lane * K;
#pragma unroll
        for (int k = 0; k < K; ++k) {
            float t0 = h0[k], t1 = h1[k], t2 = h2[k], t3 = h3[k];
            acc[k] = fmaf(d0, t0, acc[k]);
            acc[k] = fmaf(d1, t1, acc[k]);
            acc[k] = fmaf(d2, t2, acc[k]);
            acc[k] = fmaf(d3, t3, acc[k]);
        }
    }
    for (; j < j1; ++j) {
        int r = csr_src[j];
        float dr = dinv[r];
        const float* hr = h + (long)r * F + lane * K;
#pragma unroll
        for (int k = 0; k < K; ++k) acc[k] = fmaf(dr, hr[k], acc[k]);
    }
    float* ov = out + (long)v * F + lane * K;
#pragma unroll
    for (int k = 0; k < K; ++k) ov[k] = dv * acc[k];
}

// ---- naive linear for tiny FIN=3 layer -------------------------------------
__global__ void k_lin3(const float* __restrict__ h, const float* __restrict__ W,
                       const float* __restrict__ b, float* __restrict__ out, int N) {
    long tid = (long)blockIdx.x * blockDim.x + threadIdx.x;
    if (tid >= (long)N * 64) return;
    int v = (int)(tid / 64);
    int f = (int)(tid % 64);
    const float* hr = h + (long)v * 3;
    float s = b[f];
    s = fmaf(hr[0], W[0 * 64 + f], s);
    s = fmaf(hr[1], W[1 * 64 + f], s);
    s = fmaf(hr[2], W[2 * 64 + f], s);
    out[tid] = s > 0.0f ? s : 0.0f;
}

// ---- register-tiled GEMM (R4 version, proven): TILE=32 ---------------------
// 40 VGPR, 16 KB LDS, ~40% occupancy — the empirical optimum of 4 structures
// tried (R4 naive-32 / R5 tile-64 / R6 reg-pipelined / R7 LDS-staged: 60/59/
// 60/1690 us). Do not grow tile or add prefetch: regalloc kills it.
template <int FIN, int FOUT, bool RELU>
__global__ __launch_bounds__(256) void k_gemm(
        const float* __restrict__ h, const float* __restrict__ W,
        const float* __restrict__ b, float* __restrict__ out, int N) {
    constexpr int FG = FOUT / 4;    // f-groups (float4)
    constexpr int VG = 256 / FG;    // v-groups
    constexpr int VPT = 32 / VG;    // nodes per thread
    constexpr int ROWF4 = FIN / 4;  // float4s per h row
    __shared__ float hs[32][FIN];   // FIN=128 -> 16 KB
    int t = threadIdx.x;
    int fg = t % FG;
    int vg = t / FG;
    int v0 = blockIdx.x * 32;
    for (int i = t; i < 32 * ROWF4; i += 256) {
        int vv = i / ROWF4, kk = i % ROWF4;
        int vsrc = v0 + vv;
        if (vsrc >= N) vsrc = N - 1;  // tail: clamp, stores are guarded
        float4 val = ((const float4*)(h + (long)vsrc * FIN))[kk];
        *(float4*)&hs[vv][kk * 4] = val;
    }
    __syncthreads();
    float4 bias = ((const float4*)b)[fg];
    float acc[VPT][4];
#pragma unroll
    for (int i = 0; i < VPT; ++i) {
        acc[i][0] = bias.x; acc[i][1] = bias.y;
        acc[i][2] = bias.z; acc[i][3] = bias.w;
    }
    const float4* Wf4 = (const float4*)W;
#pragma unroll 4
    for (int k = 0; k < FIN; ++k) {
        float4 w = Wf4[k * FG + fg];
#pragma unroll
        for (int i = 0; i < VPT; ++i) {
            float hv = hs[vg * VPT + i][k];
            acc[i][0] = fmaf(hv, w.x, acc[i][0]);
            acc[i][1] = fmaf(hv, w.y, acc[i][1]);
            acc[i][2] = fmaf(hv, w.z, acc[i][2]);
            acc[i][3] = fmaf(hv, w.w, acc[i][3]);
        }
    }
#pragma unroll
    for (int i = 0; i < VPT; ++i) {
        int v = v0 + vg * VPT + i;
        if (v < N) {
            float4 r;
            r.x = RELU ? fmaxf(acc[i][0], 0.0f) : acc[i][0];
            r.y = RELU ? fmaxf(acc[i][1], 0.0f) : acc[i][1];
            r.z = RELU ? fmaxf(acc[i][2], 0.0f) : acc[i][2];
            r.w = RELU ? fmaxf(acc[i][3], 0.0f) : acc[i][3];
            ((float4*)(out + (long)v * FOUT))[fg] = r;
        }
    }
}

// ---- pooling: 64 nodes/block, register accumulator, flush on graph change --
#define POOL_CHUNK 64
__global__ __launch_bounds__(256) void k_pool(
        const float* __restrict__ h, const int* __restrict__ batch,
        float* __restrict__ psum, int N) {
    int tid = threadIdx.x;  // feature
    int n0 = blockIdx.x * POOL_CHUNK;
    int n1 = n0 + POOL_CHUNK;
    if (n1 > N) n1 = N;
    int gcur = batch[n0];  // sorted -> uniform scalar
    float racc = 0.0f;
    for (int n = n0; n < n1; ++n) {
        int g = batch[n];
        if (g != gcur) {
            atomicAdd(&psum[gcur * 256 + tid], racc);
            racc = 0.0f;
            gcur = g;
        }
        racc += h[(long)n * 256 + tid];
    }
    atomicAdd(&psum[gcur * 256 + tid], racc);
}

// ---- final FC --------------------------------------------------------------
__global__ void k_fc(const float* __restrict__ psum, const float* __restrict__ pcnt,
                     const float* __restrict__ Wfc, const float* __restrict__ bfc,
                     float* __restrict__ out) {
    int tid = blockIdx.x * blockDim.x + threadIdx.x;
    if (tid >= NUM_GRAPHS * NUM_CLASSES) return;
    int g = tid / NUM_CLASSES;
    int c = tid % NUM_CLASSES;
    float s = 0.0f;
#pragma unroll 8
    for (int k = 0; k < 256; ++k) s = fmaf(psum[g * 256 + k], Wfc[k * NUM_CLASSES + c], s);
    float cnt = pcnt[g];
    cnt = cnt > 1.0f ? cnt : 1.0f;
    out[tid] = s / cnt + bfc[c];
}

extern "C" void kernel_launch(void* const* d_in, const int* in_sizes, int n_in,
                              void* d_out, int out_size, void* d_ws, size_t ws_size,
                              hipStream_t stream) {
    const float* x     = (const float*)d_in[0];
    const int*   ei    = (const int*)d_in[1];
    const int*   batch = (const int*)d_in[2];
    const float* W1    = (const float*)d_in[3];
    const float* b1    = (const float*)d_in[4];
    const float* W2    = (const float*)d_in[5];
    const float* b2    = (const float*)d_in[6];
    const float* W3    = (const float*)d_in[7];
    const float* b3    = (const float*)d_in[8];
    const float* Wfc   = (const float*)d_in[9];
    const float* bfc   = (const float*)d_in[10];
    float* out = (float*)d_out;

    const int* row = ei;            // src
    const int* col = ei + N_EDGES;  // dst

    // workspace layout (~84 MB; harness ws held >=103 MB in R1)
    float* bufA   = (float*)d_ws;                        // N*256
    float* bufB   = bufA + (size_t)N_NODES * 256;        // N*128
    float* dinv   = bufB + (size_t)N_NODES * 128;        // N
    float* psum   = dinv + N_NODES;                      // 16*256
    float* pcnt   = psum + NUM_GRAPHS * 256;             // 16
    int*   degi   = (int*)(pcnt + NUM_GRAPHS);           // N
    int*   rowptr = degi + N_NODES;                      // N+1
    int*   csrsrc = rowptr + N_NODES + 1;                // E
    int*   pos    = csrsrc + N_EDGES;                    // E
    int*   bsum   = pos + N_EDGES;                       // SCAN_BLOCKS

    hipMemsetAsync(degi, 0, N_NODES * sizeof(int), stream);
    hipMemsetAsync(psum, 0, (NUM_GRAPHS * 256 + NUM_GRAPHS) * sizeof(float), stream);

    // ---- CSR build + norms (+ batch histogram fused into scan1) ----
    k_deg<<<nblk(N_EDGES), 256, 0, stream>>>(col, degi, pos, N_EDGES);
    k_scan1<<<SCAN_BLOCKS, 256, 0, stream>>>(degi, rowptr, bsum, batch, pcnt, N_NODES);
    k_scan2<<<1, 256, 0, stream>>>(bsum, SCAN_BLOCKS);
    k_scan3<<<SCAN_BLOCKS, 256, 0, stream>>>(rowptr, bsum, degi, dinv, N_NODES);
    k_fill<<<nblk(N_EDGES), 256, 0, stream>>>(row, col, rowptr, pos, csrsrc, N_EDGES);

    int prop_blocks = (N_NODES + 3) / 4;   // 4 nodes (waves) per block
    int gemm_blocks = (N_NODES + 31) / 32; // 32-node tiles

    // ---- layer 1: p1 = A~ x [N,3]; h1 = relu(p1 W1 + b1) [N,64] ----
    k_prop3<<<nblk(N_NODES), 256, 0, stream>>>(x, dinv, rowptr, csrsrc, bufB, N_NODES);
    k_lin3<<<nblk((long)N_NODES * 64), 256, 0, stream>>>(bufB, W1, b1, bufA, N_NODES);

    // ---- layer 2: p2 = A~ h1 [N,64]; h2 = relu(p2 W2 + b2) [N,128] ----
    k_prop<64><<<prop_blocks, 256, 0, stream>>>(bufA, dinv, rowptr, csrsrc, bufB, N_NODES);
    k_gemm<64, 128, true><<<gemm_blocks, 256, 0, stream>>>(bufB, W2, b2, bufA, N_NODES);

    // ---- layer 3: p3 = A~ h2 [N,128]; h3 = relu(p3 W3 + b3) [N,256] ----
    k_prop<128><<<prop_blocks, 256, 0, stream>>>(bufA, dinv, rowptr, csrsrc, bufB, N_NODES);
    k_gemm<128, 256, true><<<gemm_blocks, 256, 0, stream>>>(bufB, W3, b3, bufA, N_NODES);

    // ---- global mean pool + FC ----
    int pool_blocks = (N_NODES + POOL_CHUNK - 1) / POOL_CHUNK;
    k_pool<<<pool_blocks, 256, 0, stream>>>(bufA, batch, psum, N_NODES);
    k_fc<<<nblk(NUM_GRAPHS * NUM_CLASSES), 256, 0, stream>>>(psum, pcnt, Wfc, bfc, out);
}

// Round 9
// 342.356 us; speedup vs baseline: 5.9832x; 1.0706x over previous
//
#include <hip/hip_runtime.h>

#define N_NODES 50000
#define N_EDGES 800000
#define NUM_GRAPHS 16
#define NUM_CLASSES 247
#define SCAN_BLOCKS ((N_NODES + 255) / 256)  // 196

typedef __attribute__((ext_vector_type(8))) short bf16x8;
typedef __attribute__((ext_vector_type(4))) float f32x4;
typedef unsigned short ushort_t;

static inline int nblk(long n) { return (int)((n + 255) / 256); }

__device__ __forceinline__ float bfl(unsigned short u) {
    return __uint_as_float((unsigned)u << 16);
}
__device__ __forceinline__ unsigned short bf16_rne(float f) {
    unsigned u = __float_as_uint(f);
    u += 0x7FFF + ((u >> 16) & 1);
    return (unsigned short)(u >> 16);
}

// ---- degree histogram; atomic return value = edge rank within dst ----------
__global__ void k_deg(const int* __restrict__ col, int* __restrict__ degi,
                      int* __restrict__ pos, int E) {
    int e = blockIdx.x * blockDim.x + threadIdx.x;
    if (e < E) pos[e] = atomicAdd(&degi[col[e]], 1);
}

// ---- hierarchical exclusive scan + batch histogram (fused) -----------------
__global__ __launch_bounds__(256) void k_scan1(const int* __restrict__ degi,
                                               int* __restrict__ rowptr,
                                               int* __restrict__ bsum,
                                               const int* __restrict__ batch,
                                               float* __restrict__ pcnt, int N) {
    __shared__ int buf[256];
    __shared__ int hist[NUM_GRAPHS];
    int t = threadIdx.x;
    if (t < NUM_GRAPHS) hist[t] = 0;
    int i = blockIdx.x * 256 + t;
    int v = (i < N) ? degi[i] : 0;
    buf[t] = v;
    if (i < N) atomicAdd(&hist[batch[i]], 1);
    __syncthreads();
#pragma unroll
    for (int off = 1; off < 256; off <<= 1) {
        int tmp = (t >= off) ? buf[t - off] : 0;
        __syncthreads();
        if (t >= off) buf[t] += tmp;
        __syncthreads();
    }
    if (i < N) rowptr[i] = buf[t] - v;  // exclusive within block
    if (t == 255) bsum[blockIdx.x] = buf[255];
    if (t < NUM_GRAPHS && hist[t] > 0) atomicAdd(&pcnt[t], (float)hist[t]);
}

__global__ __launch_bounds__(256) void k_scan2(int* __restrict__ bsum, int nb) {
    __shared__ int buf[256];
    int t = threadIdx.x;
    int v = (t < nb) ? bsum[t] : 0;
    buf[t] = v;
    __syncthreads();
#pragma unroll
    for (int off = 1; off < 256; off <<= 1) {
        int tmp = (t >= off) ? buf[t - off] : 0;
        __syncthreads();
        if (t >= off) buf[t] += tmp;
        __syncthreads();
    }
    if (t < nb) bsum[t] = buf[t] - v;  // exclusive
}

__global__ __launch_bounds__(256) void k_scan3(int* __restrict__ rowptr,
                                               const int* __restrict__ bsum,
                                               const int* __restrict__ degi,
                                               float* __restrict__ dinv, int N) {
    int i = blockIdx.x * 256 + (int)threadIdx.x;
    if (i < N) {
        rowptr[i] += bsum[blockIdx.x];
        dinv[i] = rsqrtf((float)degi[i] + 1.0f);  // +1 = self loop
    }
    if (i == 0) rowptr[N] = N_EDGES;
}

// ---- CSR fill: no atomic — rank precomputed in k_deg -----------------------
__global__ void k_fill(const int* __restrict__ row, const int* __restrict__ col,
                       const int* __restrict__ rowptr, const int* __restrict__ pos,
                       int* __restrict__ csr_src, int E) {
    int e = blockIdx.x * blockDim.x + threadIdx.x;
    if (e >= E) return;
    int c = col[e];
    __builtin_nontemporal_store(row[e], &csr_src[rowptr[c] + pos[e]]);
}

// ---- cast + transpose weights: Wt[f][k] = bf16(W[k][f]) --------------------
__global__ void k_castw(const float* __restrict__ W, unsigned short* __restrict__ Wt,
                        int K, int F) {
    int i = blockIdx.x * 256 + (int)threadIdx.x;
    if (i >= K * F) return;
    int f = i / K, k = i % K;
    Wt[i] = bf16_rne(W[(long)k * F + f]);
}

// ---- propagation, F=3 (raw x), thread per node, fp32 -----------------------
__global__ void k_prop3(const float* __restrict__ x, const float* __restrict__ dinv,
                        const int* __restrict__ rowptr, const int* __restrict__ csr_src,
                        float* __restrict__ out, int N) {
    int v = blockIdx.x * blockDim.x + threadIdx.x;
    if (v >= N) return;
    float dv = dinv[v];
    float a0 = dv * x[v * 3 + 0];
    float a1 = dv * x[v * 3 + 1];
    float a2 = dv * x[v * 3 + 2];
    int j1 = rowptr[v + 1];
    for (int j = rowptr[v]; j < j1; ++j) {
        int r = csr_src[j];
        float dr = dinv[r];
        a0 += dr * x[r * 3 + 0];
        a1 += dr * x[r * 3 + 1];
        a2 += dr * x[r * 3 + 2];
    }
    out[v * 3 + 0] = dv * a0;
    out[v * 3 + 1] = dv * a1;
    out[v * 3 + 2] = dv * a2;
}

// ---- tiny linear FIN=3 -> bf16 h1 ------------------------------------------
__global__ void k_lin3(const float* __restrict__ h, const float* __restrict__ W,
                       const float* __restrict__ b, unsigned short* __restrict__ out,
                       int N) {
    long tid = (long)blockIdx.x * blockDim.x + threadIdx.x;
    if (tid >= (long)N * 64) return;
    int v = (int)(tid / 64);
    int f = (int)(tid % 64);
    const float* hr = h + (long)v * 3;
    float s = b[f];
    s = fmaf(hr[0], W[0 * 64 + f], s);
    s = fmaf(hr[1], W[1 * 64 + f], s);
    s = fmaf(hr[2], W[2 * 64 + f], s);
    out[tid] = bf16_rne(s > 0.0f ? s : 0.0f);
}

// ---- propagation over bf16 rows, fp32 accumulate, bf16 out -----------------
// wave per node; lane holds K=F/64 contiguous bf16 features.
template <int F>
__global__ __launch_bounds__(256) void k_propb(
        const unsigned short* __restrict__ h, const float* __restrict__ dinv,
        const int* __restrict__ rowptr, const int* __restrict__ csr_src,
        unsigned short* __restrict__ out, int N) {
    constexpr int K = F / 64;  // 1 or 2
    int wave = threadIdx.x >> 6;
    int lane = threadIdx.x & 63;
    int v = blockIdx.x * 4 + wave;
    if (v >= N) return;
    float dv = dinv[v];
    float acc[K];
    const unsigned short* hv = h + (long)v * F + lane * K;
    if (K == 2) {
        unsigned u = *(const unsigned*)hv;
        acc[0] = dv * __uint_as_float(u << 16);
        acc[1] = dv * __uint_as_float(u & 0xFFFF0000u);
    } else {
        acc[0] = dv * bfl(hv[0]);
    }
    int j0 = __builtin_amdgcn_readfirstlane(rowptr[v]);
    int j1 = __builtin_amdgcn_readfirstlane(rowptr[v + 1]);
    int j = j0;
    for (; j + 8 <= j1; j += 8) {
        int r[8];
        float d[8];
#pragma unroll
        for (int u = 0; u < 8; ++u) r[u] = csr_src[j + u];
#pragma unroll
        for (int u = 0; u < 8; ++u) d[u] = dinv[r[u]];
        if (K == 2) {
            unsigned tv[8];
#pragma unroll
            for (int u = 0; u < 8; ++u)
                tv[u] = *(const unsigned*)(h + (long)r[u] * F + lane * 2);
#pragma unroll
            for (int u = 0; u < 8; ++u) {
                acc[0] = fmaf(d[u], __uint_as_float(tv[u] << 16), acc[0]);
                acc[1] = fmaf(d[u], __uint_as_float(tv[u] & 0xFFFF0000u), acc[1]);
            }
        } else {
            unsigned short tv[8];
#pragma unroll
            for (int u = 0; u < 8; ++u) tv[u] = h[(long)r[u] * F + lane];
#pragma unroll
            for (int u = 0; u < 8; ++u) acc[0] = fmaf(d[u], bfl(tv[u]), acc[0]);
        }
    }
    for (; j < j1; ++j) {
        int r = csr_src[j];
        float dr = dinv[r];
        if (K == 2) {
            unsigned u = *(const unsigned*)(h + (long)r * F + lane * 2);
            acc[0] = fmaf(dr, __uint_as_float(u << 16), acc[0]);
            acc[1] = fmaf(dr, __uint_as_float(u & 0xFFFF0000u), acc[1]);
        } else {
            acc[0] = fmaf(dr, bfl(h[(long)r * F + lane]), acc[0]);
        }
    }
    unsigned short* ov = out + (long)v * F + lane * K;
#pragma unroll
    for (int k = 0; k < K; ++k) ov[k] = bf16_rne(dv * acc[k]);
}

// ---- MFMA GEMM: out[v][f] = relu(p[v][:] @ W + b), p bf16, Wt bf16[f][k] ---
// Wave per 16x16 tile. A-frag: p[m0+(lane&15)][k=quad*8+j]; B-frag (Wt is
// W^T): Wt[f0+(lane&15)][k=quad*8+j]; C/D: col=lane&15 (f), row=quad*4+reg.
// No LDS, acc = 4 fp32/lane -> no register-pressure cliff (R5-R7 lesson).
template <int K, int F, bool OUT_BF16>
__global__ __launch_bounds__(256) void k_gemm_mfma(
        const unsigned short* __restrict__ p, const unsigned short* __restrict__ Wt,
        const float* __restrict__ b, void* __restrict__ outv, int N) {
    constexpr int NF = F / 16;  // f-tiles
    int wave = threadIdx.x >> 6;
    int lane = threadIdx.x & 63;
    int tile = blockIdx.x * 4 + wave;
    int mt = tile / NF;
    int ft = tile % NF;  // block's 4 waves share mt (NF % 4 == 0) -> L1 A reuse
    int m0 = mt * 16, f0 = ft * 16;
    if (m0 >= N) return;
    int quad = lane >> 4;
    int l16 = lane & 15;
    f32x4 acc = {0.f, 0.f, 0.f, 0.f};
    const unsigned short* prow = p + (long)(m0 + l16) * K + quad * 8;
    const unsigned short* wrow = Wt + (long)(f0 + l16) * K + quad * 8;
#pragma unroll
    for (int k0 = 0; k0 < K; k0 += 32) {
        bf16x8 a = *(const bf16x8*)(const void*)(prow + k0);
        bf16x8 bb = *(const bf16x8*)(const void*)(wrow + k0);
        acc = __builtin_amdgcn_mfma_f32_16x16x32_bf16(a, bb, acc, 0, 0, 0);
    }
    float bias = b[f0 + l16];
#pragma unroll
    for (int r = 0; r < 4; ++r) {
        int m = m0 + quad * 4 + r;
        float val = fmaxf(acc[r] + bias, 0.0f);
        if constexpr (OUT_BF16) {
            ((unsigned short*)outv)[(long)m * F + f0 + l16] = bf16_rne(val);
        } else {
            ((float*)outv)[(long)m * F + f0 + l16] = val;
        }
    }
}

// ---- pooling: 64 nodes/block, register accumulator, flush on graph change --
#define POOL_CHUNK 64
__global__ __launch_bounds__(256) void k_pool(
        const float* __restrict__ h, const int* __restrict__ batch,
        float* __restrict__ psum, int N) {
    int tid = threadIdx.x;  // feature
    int n0 = blockIdx.x * POOL_CHUNK;
    int n1 = n0 + POOL_CHUNK;
    if (n1 > N) n1 = N;
    int gcur = batch[n0];  // sorted -> uniform scalar
    float racc = 0.0f;
    for (int n = n0; n < n1; ++n) {
        int g = batch[n];
        if (g != gcur) {
            atomicAdd(&psum[gcur * 256 + tid], racc);
            racc = 0.0f;
            gcur = g;
        }
        racc += h[(long)n * 256 + tid];
    }
    atomicAdd(&psum[gcur * 256 + tid], racc);
}

// ---- final FC --------------------------------------------------------------
__global__ void k_fc(const float* __restrict__ psum, const float* __restrict__ pcnt,
                     const float* __restrict__ Wfc, const float* __restrict__ bfc,
                     float* __restrict__ out) {
    int tid = blockIdx.x * blockDim.x + threadIdx.x;
    if (tid >= NUM_GRAPHS * NUM_CLASSES) return;
    int g = tid / NUM_CLASSES;
    int c = tid % NUM_CLASSES;
    float s = 0.0f;
#pragma unroll 8
    for (int k = 0; k < 256; ++k) s = fmaf(psum[g * 256 + k], Wfc[k * NUM_CLASSES + c], s);
    float cnt = pcnt[g];
    cnt = cnt > 1.0f ? cnt : 1.0f;
    out[tid] = s / cnt + bfc[c];
}

extern "C" void kernel_launch(void* const* d_in, const int* in_sizes, int n_in,
                              void* d_out, int out_size, void* d_ws, size_t ws_size,
                              hipStream_t stream) {
    const float* x     = (const float*)d_in[0];
    const int*   ei    = (const int*)d_in[1];
    const int*   batch = (const int*)d_in[2];
    const float* W1    = (const float*)d_in[3];
    const float* b1    = (const float*)d_in[4];
    const float* W2    = (const float*)d_in[5];
    const float* b2    = (const float*)d_in[6];
    const float* W3    = (const float*)d_in[7];
    const float* b3    = (const float*)d_in[8];
    const float* Wfc   = (const float*)d_in[9];
    const float* bfc   = (const float*)d_in[10];
    float* out = (float*)d_out;

    const int* row = ei;            // src
    const int* col = ei + N_EDGES;  // dst

    // workspace layout (~85 MB), all sub-arrays 16B-aligned
    float*  bufA = (float*)d_ws;                         // N*256 f32 (h3)
    float*  p1   = bufA + (size_t)N_NODES * 256;         // N*3 f32
    float*  dinv = p1 + (size_t)N_NODES * 3;             // N
    float*  psum = dinv + N_NODES;                       // 16*256
    float*  pcnt = psum + NUM_GRAPHS * 256;              // 16
    unsigned short* X   = (unsigned short*)(pcnt + NUM_GRAPHS);  // N*128 bf16
    unsigned short* Y   = X + (size_t)N_NODES * 128;             // N*128 bf16
    unsigned short* Wt2 = Y + (size_t)N_NODES * 128;             // 128*64
    unsigned short* Wt3 = Wt2 + 128 * 64;                        // 256*128
    int* degi   = (int*)(Wt3 + 256 * 128);               // N
    int* rowptr = degi + N_NODES;                        // N+1
    int* csrsrc = rowptr + N_NODES + 1;                  // E
    int* pos    = csrsrc + N_EDGES;                      // E
    int* bsum   = pos + N_EDGES;                         // SCAN_BLOCKS

    hipMemsetAsync(degi, 0, N_NODES * sizeof(int), stream);
    hipMemsetAsync(psum, 0, (NUM_GRAPHS * 256 + NUM_GRAPHS) * sizeof(float), stream);

    // ---- CSR build + norms + weight casts ----
    k_deg<<<nblk(N_EDGES), 256, 0, stream>>>(col, degi, pos, N_EDGES);
    k_scan1<<<SCAN_BLOCKS, 256, 0, stream>>>(degi, rowptr, bsum, batch, pcnt, N_NODES);
    k_scan2<<<1, 256, 0, stream>>>(bsum, SCAN_BLOCKS);
    k_scan3<<<SCAN_BLOCKS, 256, 0, stream>>>(rowptr, bsum, degi, dinv, N_NODES);
    k_fill<<<nblk(N_EDGES), 256, 0, stream>>>(row, col, rowptr, pos, csrsrc, N_EDGES);
    k_castw<<<nblk(64 * 128), 256, 0, stream>>>(W2, Wt2, 64, 128);
    k_castw<<<nblk(128 * 256), 256, 0, stream>>>(W3, Wt3, 128, 256);

    int prop_blocks = (N_NODES + 3) / 4;  // 4 nodes (waves) per block

    // ---- layer 1: p1 = A~ x [N,3]; h1 = relu(p1 W1 + b1) -> X bf16 [N,64] --
    k_prop3<<<nblk(N_NODES), 256, 0, stream>>>(x, dinv, rowptr, csrsrc, p1, N_NODES);
    k_lin3<<<nblk((long)N_NODES * 64), 256, 0, stream>>>(p1, W1, b1, X, N_NODES);

    // ---- layer 2: p2 = A~ h1 -> Y; h2 = relu(p2 W2 + b2) -> X bf16 [N,128] -
    k_propb<64><<<prop_blocks, 256, 0, stream>>>(X, dinv, rowptr, csrsrc, Y, N_NODES);
    k_gemm_mfma<64, 128, true><<<(N_NODES / 16) * (128 / 16) / 4, 256, 0, stream>>>(
        Y, Wt2, b2, X, N_NODES);

    // ---- layer 3: p3 = A~ h2 -> Y; h3 = relu(p3 W3 + b3) -> bufA f32 [N,256]
    k_propb<128><<<prop_blocks, 256, 0, stream>>>(X, dinv, rowptr, csrsrc, Y, N_NODES);
    k_gemm_mfma<128, 256, false><<<(N_NODES / 16) * (256 / 16) / 4, 256, 0, stream>>>(
        Y, Wt3, b3, bufA, N_NODES);

    // ---- global mean pool + FC ----
    int pool_blocks = (N_NODES + POOL_CHUNK - 1) / POOL_CHUNK;
    k_pool<<<pool_blocks, 256, 0, stream>>>(bufA, batch, psum, N_NODES);
    k_fc<<<nblk(NUM_GRAPHS * NUM_CLASSES), 256, 0, stream>>>(psum, pcnt, Wfc, bfc, out);
}

// Round 11
// 327.926 us; speedup vs baseline: 6.2465x; 1.0440x over previous
//
#include <hip/hip_runtime.h>

#define N_NODES 50000
#define N_EDGES 800000
#define NUM_GRAPHS 16
#define NUM_CLASSES 247
#define SCAN_BLOCKS ((N_NODES + 255) / 256)  // 196

typedef __attribute__((ext_vector_type(8))) short bf16x8;
typedef __attribute__((ext_vector_type(4))) float f32x4;

static inline int nblk(long n) { return (int)((n + 255) / 256); }

__device__ __forceinline__ float bfl(unsigned short u) {
    return __uint_as_float((unsigned)u << 16);
}
__device__ __forceinline__ unsigned short bf16_rne(float f) {
    unsigned u = __float_as_uint(f);
    u += 0x7FFF + ((u >> 16) & 1);
    return (unsigned short)(u >> 16);
}

// ---- degree histogram; atomic return value = edge rank within dst ----------
__global__ void k_deg(const int* __restrict__ col, int* __restrict__ degi,
                      int* __restrict__ pos, int E) {
    int e = blockIdx.x * blockDim.x + threadIdx.x;
    if (e < E) pos[e] = atomicAdd(&degi[col[e]], 1);
}

// ---- hierarchical exclusive scan + batch histogram (fused) -----------------
__global__ __launch_bounds__(256) void k_scan1(const int* __restrict__ degi,
                                               int* __restrict__ rowptr,
                                               int* __restrict__ bsum,
                                               const int* __restrict__ batch,
                                               float* __restrict__ pcnt, int N) {
    __shared__ int buf[256];
    __shared__ int hist[NUM_GRAPHS];
    int t = threadIdx.x;
    if (t < NUM_GRAPHS) hist[t] = 0;
    int i = blockIdx.x * 256 + t;
    int v = (i < N) ? degi[i] : 0;
    buf[t] = v;
    if (i < N) atomicAdd(&hist[batch[i]], 1);
    __syncthreads();
#pragma unroll
    for (int off = 1; off < 256; off <<= 1) {
        int tmp = (t >= off) ? buf[t - off] : 0;
        __syncthreads();
        if (t >= off) buf[t] += tmp;
        __syncthreads();
    }
    if (i < N) rowptr[i] = buf[t] - v;  // exclusive within block
    if (t == 255) bsum[blockIdx.x] = buf[255];
    if (t < NUM_GRAPHS && hist[t] > 0) atomicAdd(&pcnt[t], (float)hist[t]);
}

__global__ __launch_bounds__(256) void k_scan2(int* __restrict__ bsum, int nb) {
    __shared__ int buf[256];
    int t = threadIdx.x;
    int v = (t < nb) ? bsum[t] : 0;
    buf[t] = v;
    __syncthreads();
#pragma unroll
    for (int off = 1; off < 256; off <<= 1) {
        int tmp = (t >= off) ? buf[t - off] : 0;
        __syncthreads();
        if (t >= off) buf[t] += tmp;
        __syncthreads();
    }
    if (t < nb) bsum[t] = buf[t] - v;  // exclusive
}

__global__ __launch_bounds__(256) void k_scan3(int* __restrict__ rowptr,
                                               const int* __restrict__ bsum,
                                               const int* __restrict__ degi,
                                               float* __restrict__ dinv, int N) {
    int i = blockIdx.x * 256 + (int)threadIdx.x;
    if (i < N) {
        rowptr[i] += bsum[blockIdx.x];
        dinv[i] = rsqrtf((float)degi[i] + 1.0f);  // +1 = self loop
    }
    if (i == 0) rowptr[N] = N_EDGES;
}

// ---- CSR fill: no atomic — rank precomputed in k_deg -----------------------
__global__ void k_fill(const int* __restrict__ row, const int* __restrict__ col,
                       const int* __restrict__ rowptr, const int* __restrict__ pos,
                       int* __restrict__ csr_src, int E) {
    int e = blockIdx.x * blockDim.x + threadIdx.x;
    if (e >= E) return;
    int c = col[e];
    __builtin_nontemporal_store(row[e], &csr_src[rowptr[c] + pos[e]]);
}

// ---- cast + transpose weights: Wt[f][k] = bf16(W[k][f]) --------------------
__global__ void k_castw(const float* __restrict__ W, unsigned short* __restrict__ Wt,
                        int K, int F) {
    int i = blockIdx.x * 256 + (int)threadIdx.x;
    if (i >= K * F) return;
    int f = i / K, k = i % K;
    Wt[i] = bf16_rne(W[(long)k * F + f]);
}

// ---- propagation, F=3 (raw x), thread per node, fp32 -----------------------
__global__ void k_prop3(const float* __restrict__ x, const float* __restrict__ dinv,
                        const int* __restrict__ rowptr, const int* __restrict__ csr_src,
                        float* __restrict__ out, int N) {
    int v = blockIdx.x * blockDim.x + threadIdx.x;
    if (v >= N) return;
    float dv = dinv[v];
    float a0 = dv * x[v * 3 + 0];
    float a1 = dv * x[v * 3 + 1];
    float a2 = dv * x[v * 3 + 2];
    int j1 = rowptr[v + 1];
    for (int j = rowptr[v]; j < j1; ++j) {
        int r = csr_src[j];
        float dr = dinv[r];
        a0 += dr * x[r * 3 + 0];
        a1 += dr * x[r * 3 + 1];
        a2 += dr * x[r * 3 + 2];
    }
    out[v * 3 + 0] = dv * a0;
    out[v * 3 + 1] = dv * a1;
    out[v * 3 + 2] = dv * a2;
}

// ---- tiny linear FIN=3 -> bf16 h1 ------------------------------------------
__global__ void k_lin3(const float* __restrict__ h, const float* __restrict__ W,
                       const float* __restrict__ b, unsigned short* __restrict__ out,
                       int N) {
    long tid = (long)blockIdx.x * blockDim.x + threadIdx.x;
    if (tid >= (long)N * 64) return;
    int v = (int)(tid / 64);
    int f = (int)(tid % 64);
    const float* hr = h + (long)v * 3;
    float s = b[f];
    s = fmaf(hr[0], W[0 * 64 + f], s);
    s = fmaf(hr[1], W[1 * 64 + f], s);
    s = fmaf(hr[2], W[2 * 64 + f], s);
    out[tid] = bf16_rne(s > 0.0f ? s : 0.0f);
}

// ---- propagation over bf16 rows, fp32 accumulate, bf16 out -----------------
template <int F>
__global__ __launch_bounds__(256) void k_propb(
        const unsigned short* __restrict__ h, const float* __restrict__ dinv,
        const int* __restrict__ rowptr, const int* __restrict__ csr_src,
        unsigned short* __restrict__ out, int N) {
    constexpr int K = F / 64;  // 1 or 2
    int wave = threadIdx.x >> 6;
    int lane = threadIdx.x & 63;
    int v = blockIdx.x * 4 + wave;
    if (v >= N) return;
    float dv = dinv[v];
    float acc[K];
    const unsigned short* hv = h + (long)v * F + lane * K;
    if (K == 2) {
        unsigned u = *(const unsigned*)hv;
        acc[0] = dv * __uint_as_float(u << 16);
        acc[1] = dv * __uint_as_float(u & 0xFFFF0000u);
    } else {
        acc[0] = dv * bfl(hv[0]);
    }
    int j0 = __builtin_amdgcn_readfirstlane(rowptr[v]);
    int j1 = __builtin_amdgcn_readfirstlane(rowptr[v + 1]);
    int j = j0;
    for (; j + 8 <= j1; j += 8) {
        int r[8];
        float d[8];
#pragma unroll
        for (int u = 0; u < 8; ++u) r[u] = csr_src[j + u];
#pragma unroll
        for (int u = 0; u < 8; ++u) d[u] = dinv[r[u]];
        if (K == 2) {
            unsigned tv[8];
#pragma unroll
            for (int u = 0; u < 8; ++u)
                tv[u] = *(const unsigned*)(h + (long)r[u] * F + lane * 2);
#pragma unroll
            for (int u = 0; u < 8; ++u) {
                acc[0] = fmaf(d[u], __uint_as_float(tv[u] << 16), acc[0]);
                acc[1] = fmaf(d[u], __uint_as_float(tv[u] & 0xFFFF0000u), acc[1]);
            }
        } else {
            unsigned short tv[8];
#pragma unroll
            for (int u = 0; u < 8; ++u) tv[u] = h[(long)r[u] * F + lane];
#pragma unroll
            for (int u = 0; u < 8; ++u) acc[0] = fmaf(d[u], bfl(tv[u]), acc[0]);
        }
    }
    for (; j < j1; ++j) {
        int r = csr_src[j];
        float dr = dinv[r];
        if (K == 2) {
            unsigned u = *(const unsigned*)(h + (long)r * F + lane * 2);
            acc[0] = fmaf(dr, __uint_as_float(u << 16), acc[0]);
            acc[1] = fmaf(dr, __uint_as_float(u & 0xFFFF0000u), acc[1]);
        } else {
            acc[0] = fmaf(dr, bfl(h[(long)r * F + lane]), acc[0]);
        }
    }
    unsigned short* ov = out + (long)v * F + lane * K;
#pragma unroll
    for (int k = 0; k < K; ++k) ov[k] = bf16_rne(dv * acc[k]);
}

// ---- MFMA GEMM: 4 m-tiles per wave, B-frags register-cached ----------------
// Wave = (m-group of 64 rows, ft). B-frag per k0 loaded once, reused over the
// 4 A-tiles -> 16 MFMAs/wave (K=128). Block's 4 waves share the same A rows
// (consecutive ft, same mg since NF%4==0) -> L1 A reuse. acc 16 + B 4*KB +
// A-temps ~= 70 VGPR, no spill cliff (R7 lesson).
// Layouts (verified R9): A[m=l16][k=quad*8+j], B=Wt[f=l16][k=quad*8+j],
// C/D col=l16(f), row=quad*4+reg.
template <int K, int F, bool OUT_BF16>
__global__ __launch_bounds__(256) void k_gemm_mfma(
        const unsigned short* __restrict__ p, const unsigned short* __restrict__ Wt,
        const float* __restrict__ b, void* __restrict__ outv, int N) {
    constexpr int NF = F / 16;   // f-tiles (8 or 16)
    constexpr int KB = K / 32;   // k-blocks (2 or 4)
    int wave = threadIdx.x >> 6;
    int lane = threadIdx.x & 63;
    int gw = blockIdx.x * 4 + wave;
    int mg = gw / NF;            // m-group (64 rows)
    int ft = gw % NF;
    int m0 = mg * 64;
    if (m0 >= N) return;
    int quad = lane >> 4;
    int l16 = lane & 15;
    int f0 = ft * 16;
    const unsigned short* wrow = Wt + (long)(f0 + l16) * K + quad * 8;
    bf16x8 bfr[KB];
#pragma unroll
    for (int kb = 0; kb < KB; ++kb)
        bfr[kb] = *(const bf16x8*)(const void*)(wrow + kb * 32);
    f32x4 acc[4];
#pragma unroll
    for (int mi = 0; mi < 4; ++mi) acc[mi] = {0.f, 0.f, 0.f, 0.f};
    int mvalid = (N - m0 + 15) / 16;  // 1..4 valid m-tiles
    if (mvalid > 4) mvalid = 4;
#pragma unroll
    for (int mi = 0; mi < 4; ++mi) {
        if (mi >= mvalid) break;
        const unsigned short* prow = p + (long)(m0 + mi * 16 + l16) * K + quad * 8;
#pragma unroll
        for (int kb = 0; kb < KB; ++kb) {
            bf16x8 a = *(const bf16x8*)(const void*)(prow + kb * 32);
            acc[mi] = __builtin_amdgcn_mfma_f32_16x16x32_bf16(a, bfr[kb], acc[mi], 0, 0, 0);
        }
    }
    float bias = b[f0 + l16];
#pragma unroll
    for (int mi = 0; mi < 4; ++mi) {
        if (mi >= mvalid) break;
#pragma unroll
        for (int r = 0; r < 4; ++r) {
            int m = m0 + mi * 16 + quad * 4 + r;
            float val = fmaxf(acc[mi][r] + bias, 0.0f);
            if constexpr (OUT_BF16) {
                ((unsigned short*)outv)[(long)m * F + f0 + l16] = bf16_rne(val);
            } else {
                ((float*)outv)[(long)m * F + f0 + l16] = val;
            }
        }
    }
}

// ---- pooling over bf16 h3: 64 nodes/block, register acc, flush on change ---
#define POOL_CHUNK 64
__global__ __launch_bounds__(256) void k_pool(
        const unsigned short* __restrict__ h, const int* __restrict__ batch,
        float* __restrict__ psum, int N) {
    int tid = threadIdx.x;  // feature
    int n0 = blockIdx.x * POOL_CHUNK;
    int n1 = n0 + POOL_CHUNK;
    if (n1 > N) n1 = N;
    int gcur = batch[n0];  // sorted -> uniform scalar
    float racc = 0.0f;
    for (int n = n0; n < n1; ++n) {
        int g = batch[n];
        if (g != gcur) {
            atomicAdd(&psum[gcur * 256 + tid], racc);
            racc = 0.0f;
            gcur = g;
        }
        racc += bfl(h[(long)n * 256 + tid]);
    }
    atomicAdd(&psum[gcur * 256 + tid], racc);
}

// ---- final FC --------------------------------------------------------------
__global__ void k_fc(const float* __restrict__ psum, const float* __restrict__ pcnt,
                     const float* __restrict__ Wfc, const float* __restrict__ bfc,
                     float* __restrict__ out) {
    int tid = blockIdx.x * blockDim.x + threadIdx.x;
    if (tid >= NUM_GRAPHS * NUM_CLASSES) return;
    int g = tid / NUM_CLASSES;
    int c = tid % NUM_CLASSES;
    float s = 0.0f;
#pragma unroll 8
    for (int k = 0; k < 256; ++k) s = fmaf(psum[g * 256 + k], Wfc[k * NUM_CLASSES + c], s);
    float cnt = pcnt[g];
    cnt = cnt > 1.0f ? cnt : 1.0f;
    out[tid] = s / cnt + bfc[c];
}

extern "C" void kernel_launch(void* const* d_in, const int* in_sizes, int n_in,
                              void* d_out, int out_size, void* d_ws, size_t ws_size,
                              hipStream_t stream) {
    const float* x     = (const float*)d_in[0];
    const int*   ei    = (const int*)d_in[1];
    const int*   batch = (const int*)d_in[2];
    const float* W1    = (const float*)d_in[3];
    const float* b1    = (const float*)d_in[4];
    const float* W2    = (const float*)d_in[5];
    const float* b2    = (const float*)d_in[6];
    const float* W3    = (const float*)d_in[7];
    const float* b3    = (const float*)d_in[8];
    const float* Wfc   = (const float*)d_in[9];
    const float* bfc   = (const float*)d_in[10];
    float* out = (float*)d_out;

    const int* row = ei;            // src
    const int* col = ei + N_EDGES;  // dst

    // workspace layout (~85 MB), all bf16 arrays 16B-aligned
    float*  bufA = (float*)d_ws;                         // N*256 f32 (h3 bf16 lives here)
    float*  p1   = bufA + (size_t)N_NODES * 256;         // N*3 f32
    float*  dinv = p1 + (size_t)N_NODES * 3;             // N
    float*  psum = dinv + N_NODES;                       // 16*256
    float*  pcnt = psum + NUM_GRAPHS * 256;              // 16
    unsigned short* X   = (unsigned short*)(pcnt + NUM_GRAPHS);  // N*128 bf16
    unsigned short* Y   = X + (size_t)N_NODES * 128;             // N*128 bf16
    unsigned short* Wt2 = Y + (size_t)N_NODES * 128;             // 128*64
    unsigned short* Wt3 = Wt2 + 128 * 64;                        // 256*128
    unsigned short* H3  = (unsigned short*)bufA;                 // N*256 bf16
    int* degi   = (int*)(Wt3 + 256 * 128);               // N
    int* rowptr = degi + N_NODES;                        // N+1
    int* csrsrc = rowptr + N_NODES + 1;                  // E
    int* pos    = csrsrc + N_EDGES;                      // E
    int* bsum   = pos + N_EDGES;                         // SCAN_BLOCKS

    hipMemsetAsync(degi, 0, N_NODES * sizeof(int), stream);
    hipMemsetAsync(psum, 0, (NUM_GRAPHS * 256 + NUM_GRAPHS) * sizeof(float), stream);

    // ---- CSR build + norms + weight casts ----
    k_deg<<<nblk(N_EDGES), 256, 0, stream>>>(col, degi, pos, N_EDGES);
    k_scan1<<<SCAN_BLOCKS, 256, 0, stream>>>(degi, rowptr, bsum, batch, pcnt, N_NODES);
    k_scan2<<<1, 256, 0, stream>>>(bsum, SCAN_BLOCKS);
    k_scan3<<<SCAN_BLOCKS, 256, 0, stream>>>(rowptr, bsum, degi, dinv, N_NODES);
    k_fill<<<nblk(N_EDGES), 256, 0, stream>>>(row, col, rowptr, pos, csrsrc, N_EDGES);
    k_castw<<<nblk(64 * 128), 256, 0, stream>>>(W2, Wt2, 64, 128);
    k_castw<<<nblk(128 * 256), 256, 0, stream>>>(W3, Wt3, 128, 256);

    int prop_blocks = (N_NODES + 3) / 4;        // 4 nodes (waves) per block
    int mgroups = (N_NODES / 16 + 3) / 4;       // 782 m-groups of 64 rows

    // ---- layer 1: p1 = A~ x [N,3]; h1 = relu(p1 W1 + b1) -> X bf16 [N,64] --
    k_prop3<<<nblk(N_NODES), 256, 0, stream>>>(x, dinv, rowptr, csrsrc, p1, N_NODES);
    k_lin3<<<nblk((long)N_NODES * 64), 256, 0, stream>>>(p1, W1, b1, X, N_NODES);

    // ---- layer 2: p2 = A~ h1 -> Y; h2 = relu(p2 W2 + b2) -> X bf16 [N,128] -
    k_propb<64><<<prop_blocks, 256, 0, stream>>>(X, dinv, rowptr, csrsrc, Y, N_NODES);
    k_gemm_mfma<64, 128, true><<<mgroups * 8 / 4, 256, 0, stream>>>(Y, Wt2, b2, X, N_NODES);

    // ---- layer 3: p3 = A~ h2 -> Y; h3 = relu(p3 W3 + b3) -> H3 bf16 [N,256]
    k_propb<128><<<prop_blocks, 256, 0, stream>>>(X, dinv, rowptr, csrsrc, Y, N_NODES);
    k_gemm_mfma<128, 256, true><<<mgroups * 16 / 4, 256, 0, stream>>>(Y, Wt3, b3, H3, N_NODES);

    // ---- global mean pool + FC ----
    int pool_blocks = (N_NODES + POOL_CHUNK - 1) / POOL_CHUNK;
    k_pool<<<pool_blocks, 256, 0, stream>>>(H3, batch, psum, N_NODES);
    k_fc<<<nblk(NUM_GRAPHS * NUM_CLASSES), 256, 0, stream>>>(psum, pcnt, Wfc, bfc, out);
}

// Round 12
// 299.781 us; speedup vs baseline: 6.8329x; 1.0939x over previous
//
#include <hip/hip_runtime.h>

#define N_NODES 50000
#define N_EDGES 800000
#define NUM_GRAPHS 16
#define NUM_CLASSES 247
#define SCAN_BLOCKS ((N_NODES + 255) / 256)  // 196

typedef __attribute__((ext_vector_type(8))) short bf16x8;
typedef __attribute__((ext_vector_type(4))) float f32x4;

static inline int nblk(long n) { return (int)((n + 255) / 256); }

__device__ __forceinline__ float bfl(unsigned short u) {
    return __uint_as_float((unsigned)u << 16);
}
__device__ __forceinline__ unsigned short bf16_rne(float f) {
    unsigned u = __float_as_uint(f);
    u += 0x7FFF + ((u >> 16) & 1);
    return (unsigned short)(u >> 16);
}

// ---- degree histogram; atomic return value = edge rank within dst ----------
__global__ void k_deg(const int* __restrict__ col, int* __restrict__ degi,
                      int* __restrict__ pos, int E) {
    int e = blockIdx.x * blockDim.x + threadIdx.x;
    if (e < E) pos[e] = atomicAdd(&degi[col[e]], 1);
}

// ---- scan phase 1: per-block exclusive scan + block sums + batch histogram -
__global__ __launch_bounds__(256) void k_scan1(const int* __restrict__ degi,
                                               int* __restrict__ rowptr,
                                               int* __restrict__ bsum,
                                               const int* __restrict__ batch,
                                               float* __restrict__ pcnt, int N) {
    __shared__ int buf[256];
    __shared__ int hist[NUM_GRAPHS];
    int t = threadIdx.x;
    if (t < NUM_GRAPHS) hist[t] = 0;
    int i = blockIdx.x * 256 + t;
    int v = (i < N) ? degi[i] : 0;
    buf[t] = v;
    if (i < N) atomicAdd(&hist[batch[i]], 1);
    __syncthreads();
#pragma unroll
    for (int off = 1; off < 256; off <<= 1) {
        int tmp = (t >= off) ? buf[t - off] : 0;
        __syncthreads();
        if (t >= off) buf[t] += tmp;
        __syncthreads();
    }
    if (i < N) rowptr[i] = buf[t] - v;  // exclusive within block
    if (t == 255) bsum[blockIdx.x] = buf[255];
    if (t < NUM_GRAPHS && hist[t] > 0) atomicAdd(&pcnt[t], (float)hist[t]);
}

// ---- scan phase 2 (folded): each block reduces its own bsum prefix; also ---
// computes dinv and pre-scaled xs = dinv*x (removes dinv gather from layer1).
__global__ __launch_bounds__(256) void k_scan3(int* __restrict__ rowptr,
                                               const int* __restrict__ bsum,
                                               const int* __restrict__ degi,
                                               float* __restrict__ dinv,
                                               const float* __restrict__ x,
                                               float* __restrict__ xs, int N) {
    __shared__ int red[256];
    int t = threadIdx.x;
    int b = blockIdx.x;
    red[t] = (t < b) ? bsum[t] : 0;  // b <= SCAN_BLOCKS-1 <= 195 < 256
    __syncthreads();
#pragma unroll
    for (int off = 128; off > 0; off >>= 1) {
        if (t < off) red[t] += red[t + off];
        __syncthreads();
    }
    int boff = red[0];
    int i = b * 256 + t;
    if (i < N) {
        rowptr[i] += boff;
        float dv = rsqrtf((float)degi[i] + 1.0f);  // +1 = self loop
        dinv[i] = dv;
        xs[i * 3 + 0] = dv * x[i * 3 + 0];
        xs[i * 3 + 1] = dv * x[i * 3 + 1];
        xs[i * 3 + 2] = dv * x[i * 3 + 2];
    }
    if (i == 0) rowptr[N] = N_EDGES;
}

// ---- CSR fill: no atomic (rank precomputed); plain store (nt hurt, R6) -----
__global__ void k_fill(const int* __restrict__ row, const int* __restrict__ col,
                       const int* __restrict__ rowptr, const int* __restrict__ pos,
                       int* __restrict__ csr_src, int E) {
    int e = blockIdx.x * blockDim.x + threadIdx.x;
    if (e >= E) return;
    int c = col[e];
    csr_src[rowptr[c] + pos[e]] = row[e];
}

// ---- merged weight cast+transpose: Wt[f][k] = bf16(W[k][f]) ----------------
__global__ void k_castw(const float* __restrict__ W2, const float* __restrict__ W3,
                        unsigned short* __restrict__ Wt2,
                        unsigned short* __restrict__ Wt3) {
    int i = blockIdx.x * 256 + (int)threadIdx.x;
    if (i < 64 * 128) {             // Wt2: [f=128][k=64]
        int f = i / 64, k = i % 64;
        Wt2[i] = bf16_rne(W2[k * 128 + f]);
    } else if (i < 64 * 128 + 128 * 256) {  // Wt3: [f=256][k=128]
        int j = i - 64 * 128;
        int f = j / 128, k = j % 128;
        Wt3[j] = bf16_rne(W3[k * 256 + f]);
    }
}

// ---- fused layer 1: p1 = dv*(xs[v]+Σxs[r]); h1' = dv*relu(p1 W1 + b1) ------
// thread per node; W1/b1 reads are wave-uniform (scalar pipe).
__global__ void k_layer1(const float* __restrict__ xs, const float* __restrict__ dinv,
                         const int* __restrict__ rowptr, const int* __restrict__ csr_src,
                         const float* __restrict__ W1, const float* __restrict__ b1,
                         unsigned short* __restrict__ out, int N) {
    int v = blockIdx.x * blockDim.x + threadIdx.x;
    if (v >= N) return;
    float a0 = xs[v * 3 + 0];
    float a1 = xs[v * 3 + 1];
    float a2 = xs[v * 3 + 2];
    int j1 = rowptr[v + 1];
    for (int j = rowptr[v]; j < j1; ++j) {
        int r = csr_src[j];
        a0 += xs[r * 3 + 0];
        a1 += xs[r * 3 + 1];
        a2 += xs[r * 3 + 2];
    }
    float dv = dinv[v];
    float p0 = dv * a0, p1 = dv * a1, p2 = dv * a2;
    unsigned short* ov = out + (long)v * 64;
#pragma unroll
    for (int f = 0; f < 64; f += 2) {
        float s0 = fmaf(p0, W1[f],     fmaf(p1, W1[64 + f],     fmaf(p2, W1[128 + f],     b1[f])));
        float s1 = fmaf(p0, W1[f + 1], fmaf(p1, W1[64 + f + 1], fmaf(p2, W1[128 + f + 1], b1[f + 1])));
        s0 = fmaxf(s0, 0.0f) * dv;  // pre-scale for next prop
        s1 = fmaxf(s1, 0.0f) * dv;
        unsigned pk = (unsigned)bf16_rne(s0) | ((unsigned)bf16_rne(s1) << 16);
        *(unsigned*)(ov + f) = pk;
    }
}

// ---- propagation over pre-scaled bf16 rows: out = bf16(dv*(h'[v]+Σh'[r])) --
// Inner loop is pure adds — no dinv gather (pre-scale trick).
template <int F>
__global__ __launch_bounds__(256) void k_propb(
        const unsigned short* __restrict__ h, const float* __restrict__ dinv,
        const int* __restrict__ rowptr, const int* __restrict__ csr_src,
        unsigned short* __restrict__ out, int N) {
    constexpr int K = F / 64;  // 1 or 2
    int wave = threadIdx.x >> 6;
    int lane = threadIdx.x & 63;
    int v = blockIdx.x * 4 + wave;
    if (v >= N) return;
    float acc[K];
    const unsigned short* hv = h + (long)v * F + lane * K;
    if (K == 2) {
        unsigned u = *(const unsigned*)hv;
        acc[0] = __uint_as_float(u << 16);
        acc[1] = __uint_as_float(u & 0xFFFF0000u);
    } else {
        acc[0] = bfl(hv[0]);
    }
    int j0 = __builtin_amdgcn_readfirstlane(rowptr[v]);
    int j1 = __builtin_amdgcn_readfirstlane(rowptr[v + 1]);
    int j = j0;
    for (; j + 8 <= j1; j += 8) {
        int r[8];
#pragma unroll
        for (int u = 0; u < 8; ++u) r[u] = csr_src[j + u];
        if (K == 2) {
            unsigned tv[8];
#pragma unroll
            for (int u = 0; u < 8; ++u)
                tv[u] = *(const unsigned*)(h + (long)r[u] * F + lane * 2);
#pragma unroll
            for (int u = 0; u < 8; ++u) {
                acc[0] += __uint_as_float(tv[u] << 16);
                acc[1] += __uint_as_float(tv[u] & 0xFFFF0000u);
            }
        } else {
            unsigned short tv[8];
#pragma unroll
            for (int u = 0; u < 8; ++u) tv[u] = h[(long)r[u] * F + lane];
#pragma unroll
            for (int u = 0; u < 8; ++u) acc[0] += bfl(tv[u]);
        }
    }
    for (; j < j1; ++j) {
        int r = csr_src[j];
        if (K == 2) {
            unsigned u = *(const unsigned*)(h + (long)r * F + lane * 2);
            acc[0] += __uint_as_float(u << 16);
            acc[1] += __uint_as_float(u & 0xFFFF0000u);
        } else {
            acc[0] += bfl(h[(long)r * F + lane]);
        }
    }
    float dv = dinv[v];
    unsigned short* ov = out + (long)v * F + lane * K;
#pragma unroll
    for (int k = 0; k < K; ++k) ov[k] = bf16_rne(dv * acc[k]);
}

// ---- MFMA GEMM: 4 m-tiles/wave, B register-cached; PRESCALE epilogue -------
// Layouts (verified R9): A[m=l16][k=quad*8+j], B=Wt[f=l16][k=quad*8+j],
// C/D col=l16(f), row=quad*4+reg. Clean unrolled full path + guarded tail.
template <int K, int F, bool PRESCALE>
__global__ __launch_bounds__(256) void k_gemm_mfma(
        const unsigned short* __restrict__ p, const unsigned short* __restrict__ Wt,
        const float* __restrict__ b, const float* __restrict__ dinv,
        unsigned short* __restrict__ out, int N) {
    constexpr int NF = F / 16;   // f-tiles (8 or 16)
    constexpr int KB = K / 32;   // k-blocks (2 or 4)
    int wave = threadIdx.x >> 6;
    int lane = threadIdx.x & 63;
    int gw = blockIdx.x * 4 + wave;
    int mg = gw / NF;            // m-group (64 rows)
    int ft = gw % NF;
    int m0 = mg * 64;
    if (m0 >= N) return;
    int quad = lane >> 4;
    int l16 = lane & 15;
    int f0 = ft * 16;
    const unsigned short* wrow = Wt + (long)(f0 + l16) * K + quad * 8;
    bf16x8 bfr[KB];
#pragma unroll
    for (int kb = 0; kb < KB; ++kb)
        bfr[kb] = *(const bf16x8*)(const void*)(wrow + kb * 32);
    f32x4 acc[4];
#pragma unroll
    for (int mi = 0; mi < 4; ++mi) acc[mi] = {0.f, 0.f, 0.f, 0.f};
    float bias = b[f0 + l16];
    if (m0 + 64 <= N) {  // full path (all but the last m-group)
#pragma unroll
        for (int mi = 0; mi < 4; ++mi) {
            const unsigned short* prow = p + (long)(m0 + mi * 16 + l16) * K + quad * 8;
#pragma unroll
            for (int kb = 0; kb < KB; ++kb) {
                bf16x8 a = *(const bf16x8*)(const void*)(prow + kb * 32);
                acc[mi] = __builtin_amdgcn_mfma_f32_16x16x32_bf16(a, bfr[kb], acc[mi], 0, 0, 0);
            }
        }
#pragma unroll
        for (int mi = 0; mi < 4; ++mi) {
#pragma unroll
            for (int r = 0; r < 4; ++r) {
                int m = m0 + mi * 16 + quad * 4 + r;
                float val = fmaxf(acc[mi][r] + bias, 0.0f);
                if (PRESCALE) val *= dinv[m];
                out[(long)m * F + f0 + l16] = bf16_rne(val);
            }
        }
    } else {  // tail m-group
        int mvalid = (N - m0 + 15) / 16;
        for (int mi = 0; mi < mvalid; ++mi) {
            const unsigned short* prow = p + (long)(m0 + mi * 16 + l16) * K + quad * 8;
#pragma unroll
            for (int kb = 0; kb < KB; ++kb) {
                bf16x8 a = *(const bf16x8*)(const void*)(prow + kb * 32);
                acc[mi] = __builtin_amdgcn_mfma_f32_16x16x32_bf16(a, bfr[kb], acc[mi], 0, 0, 0);
            }
        }
        for (int mi = 0; mi < mvalid; ++mi) {
#pragma unroll
            for (int r = 0; r < 4; ++r) {
                int m = m0 + mi * 16 + quad * 4 + r;
                float val = fmaxf(acc[mi][r] + bias, 0.0f);
                if (PRESCALE) val *= dinv[m];
                out[(long)m * F + f0 + l16] = bf16_rne(val);
            }
        }
    }
}

// ---- pooling over bf16 h3: 64 nodes/block, register acc, flush on change ---
#define POOL_CHUNK 64
__global__ __launch_bounds__(256) void k_pool(
        const unsigned short* __restrict__ h, const int* __restrict__ batch,
        float* __restrict__ psum, int N) {
    int tid = threadIdx.x;  // feature
    int n0 = blockIdx.x * POOL_CHUNK;
    int n1 = n0 + POOL_CHUNK;
    if (n1 > N) n1 = N;
    int gcur = batch[n0];  // sorted -> uniform scalar
    float racc = 0.0f;
    for (int n = n0; n < n1; ++n) {
        int g = batch[n];
        if (g != gcur) {
            atomicAdd(&psum[gcur * 256 + tid], racc);
            racc = 0.0f;
            gcur = g;
        }
        racc += bfl(h[(long)n * 256 + tid]);
    }
    atomicAdd(&psum[gcur * 256 + tid], racc);
}

// ---- final FC --------------------------------------------------------------
__global__ void k_fc(const float* __restrict__ psum, const float* __restrict__ pcnt,
                     const float* __restrict__ Wfc, const float* __restrict__ bfc,
                     float* __restrict__ out) {
    int tid = blockIdx.x * blockDim.x + threadIdx.x;
    if (tid >= NUM_GRAPHS * NUM_CLASSES) return;
    int g = tid / NUM_CLASSES;
    int c = tid % NUM_CLASSES;
    float s = 0.0f;
#pragma unroll 8
    for (int k = 0; k < 256; ++k) s = fmaf(psum[g * 256 + k], Wfc[k * NUM_CLASSES + c], s);
    float cnt = pcnt[g];
    cnt = cnt > 1.0f ? cnt : 1.0f;
    out[tid] = s / cnt + bfc[c];
}

extern "C" void kernel_launch(void* const* d_in, const int* in_sizes, int n_in,
                              void* d_out, int out_size, void* d_ws, size_t ws_size,
                              hipStream_t stream) {
    const float* x     = (const float*)d_in[0];
    const int*   ei    = (const int*)d_in[1];
    const int*   batch = (const int*)d_in[2];
    const float* W1    = (const float*)d_in[3];
    const float* b1    = (const float*)d_in[4];
    const float* W2    = (const float*)d_in[5];
    const float* b2    = (const float*)d_in[6];
    const float* W3    = (const float*)d_in[7];
    const float* b3    = (const float*)d_in[8];
    const float* Wfc   = (const float*)d_in[9];
    const float* bfc   = (const float*)d_in[10];
    float* out = (float*)d_out;

    const int* row = ei;            // src
    const int* col = ei + N_EDGES;  // dst

    // workspace layout (~85 MB), bf16 arrays 16B-aligned
    float*  bufA = (float*)d_ws;                         // N*256 f32 (H3 bf16 lives here)
    float*  xs   = bufA + (size_t)N_NODES * 256;         // N*3 f32 (pre-scaled x)
    float*  dinv = xs + (size_t)N_NODES * 3;             // N
    float*  psum = dinv + N_NODES;                       // 16*256
    float*  pcnt = psum + NUM_GRAPHS * 256;              // 16
    unsigned short* X   = (unsigned short*)(pcnt + NUM_GRAPHS);  // N*128 bf16
    unsigned short* Y   = X + (size_t)N_NODES * 128;             // N*128 bf16
    unsigned short* Wt2 = Y + (size_t)N_NODES * 128;             // 128*64
    unsigned short* Wt3 = Wt2 + 128 * 64;                        // 256*128
    unsigned short* H3  = (unsigned short*)bufA;                 // N*256 bf16
    int* degi   = (int*)(Wt3 + 256 * 128);               // N
    int* rowptr = degi + N_NODES;                        // N+1
    int* csrsrc = rowptr + N_NODES + 1;                  // E
    int* pos    = csrsrc + N_EDGES;                      // E
    int* bsum   = pos + N_EDGES;                         // SCAN_BLOCKS

    hipMemsetAsync(degi, 0, N_NODES * sizeof(int), stream);
    hipMemsetAsync(psum, 0, (NUM_GRAPHS * 256 + NUM_GRAPHS) * sizeof(float), stream);

    // ---- CSR build + norms + pre-scaled x + weight casts ----
    k_deg<<<nblk(N_EDGES), 256, 0, stream>>>(col, degi, pos, N_EDGES);
    k_scan1<<<SCAN_BLOCKS, 256, 0, stream>>>(degi, rowptr, bsum, batch, pcnt, N_NODES);
    k_scan3<<<SCAN_BLOCKS, 256, 0, stream>>>(rowptr, bsum, degi, dinv, x, xs, N_NODES);
    k_fill<<<nblk(N_EDGES), 256, 0, stream>>>(row, col, rowptr, pos, csrsrc, N_EDGES);
    k_castw<<<nblk(64 * 128 + 128 * 256), 256, 0, stream>>>(W2, W3, Wt2, Wt3);

    int prop_blocks = (N_NODES + 3) / 4;        // 4 nodes (waves) per block
    int mgroups = (N_NODES / 16 + 3) / 4;       // 782 m-groups of 64 rows

    // ---- layer 1 (fused prop+linear): X = h1' = d*relu((A~x)W1+b1), bf16 ---
    k_layer1<<<nblk(N_NODES), 256, 0, stream>>>(xs, dinv, rowptr, csrsrc, W1, b1, X, N_NODES);

    // ---- layer 2: Y = p2 = A~-apply(X); X = h2' = d*relu(Y W2 + b2) --------
    k_propb<64><<<prop_blocks, 256, 0, stream>>>(X, dinv, rowptr, csrsrc, Y, N_NODES);
    k_gemm_mfma<64, 128, true><<<mgroups * 8 / 4, 256, 0, stream>>>(Y, Wt2, b2, dinv, X, N_NODES);

    // ---- layer 3: Y = p3; H3 = h3 = relu(Y W3 + b3) (unscaled, bf16) -------
    k_propb<128><<<prop_blocks, 256, 0, stream>>>(X, dinv, rowptr, csrsrc, Y, N_NODES);
    k_gemm_mfma<128, 256, false><<<mgroups * 16 / 4, 256, 0, stream>>>(Y, Wt3, b3, dinv, H3, N_NODES);

    // ---- global mean pool + FC ----
    int pool_blocks = (N_NODES + POOL_CHUNK - 1) / POOL_CHUNK;
    k_pool<<<pool_blocks, 256, 0, stream>>>(H3, batch, psum, N_NODES);
    k_fc<<<nblk(NUM_GRAPHS * NUM_CLASSES), 256, 0, stream>>>(psum, pcnt, Wfc, bfc, out);
}

// Round 13
// 286.487 us; speedup vs baseline: 7.1500x; 1.0464x over previous
//
#include <hip/hip_runtime.h>

#define N_NODES 50000
#define N_EDGES 800000
#define NUM_GRAPHS 16
#define NUM_CLASSES 247
#define SCAN_BLOCKS ((N_NODES + 255) / 256)  // 196

typedef __attribute__((ext_vector_type(8))) short bf16x8;
typedef __attribute__((ext_vector_type(4))) float f32x4;

static inline int nblk(long n) { return (int)((n + 255) / 256); }

__device__ __forceinline__ float bfl(unsigned short u) {
    return __uint_as_float((unsigned)u << 16);
}
__device__ __forceinline__ unsigned short bf16_rne(float f) {
    unsigned u = __float_as_uint(f);
    u += 0x7FFF + ((u >> 16) & 1);
    return (unsigned short)(u >> 16);
}

// ---- degree histogram; atomic return value = edge rank within dst ----------
__global__ void k_deg(const int* __restrict__ col, int* __restrict__ degi,
                      int* __restrict__ pos, int E) {
    int e = blockIdx.x * blockDim.x + threadIdx.x;
    if (e < E) pos[e] = atomicAdd(&degi[col[e]], 1);
}

// ---- scan phase 1: per-block exclusive scan + block sums + batch histogram -
__global__ __launch_bounds__(256) void k_scan1(const int* __restrict__ degi,
                                               int* __restrict__ rowptr,
                                               int* __restrict__ bsum,
                                               const int* __restrict__ batch,
                                               float* __restrict__ pcnt, int N) {
    __shared__ int buf[256];
    __shared__ int hist[NUM_GRAPHS];
    int t = threadIdx.x;
    if (t < NUM_GRAPHS) hist[t] = 0;
    int i = blockIdx.x * 256 + t;
    int v = (i < N) ? degi[i] : 0;
    buf[t] = v;
    if (i < N) atomicAdd(&hist[batch[i]], 1);
    __syncthreads();
#pragma unroll
    for (int off = 1; off < 256; off <<= 1) {
        int tmp = (t >= off) ? buf[t - off] : 0;
        __syncthreads();
        if (t >= off) buf[t] += tmp;
        __syncthreads();
    }
    if (i < N) rowptr[i] = buf[t] - v;  // exclusive within block
    if (t == 255) bsum[blockIdx.x] = buf[255];
    if (t < NUM_GRAPHS && hist[t] > 0) atomicAdd(&pcnt[t], (float)hist[t]);
}

// ---- scan phase 2 (folded) + dinv + pre-scaled xs + weight casts -----------
__global__ __launch_bounds__(256) void k_scan3(int* __restrict__ rowptr,
                                               const int* __restrict__ bsum,
                                               const int* __restrict__ degi,
                                               float* __restrict__ dinv,
                                               const float* __restrict__ x,
                                               float* __restrict__ xs,
                                               const float* __restrict__ W2,
                                               const float* __restrict__ W3,
                                               unsigned short* __restrict__ Wt2,
                                               unsigned short* __restrict__ Wt3,
                                               int N) {
    __shared__ int red[256];
    int t = threadIdx.x;
    int b = blockIdx.x;
    red[t] = (t < b) ? bsum[t] : 0;  // b <= 195 < 256
    __syncthreads();
#pragma unroll
    for (int off = 128; off > 0; off >>= 1) {
        if (t < off) red[t] += red[t + off];
        __syncthreads();
    }
    int boff = red[0];
    int i = b * 256 + t;
    if (i < N) {
        rowptr[i] += boff;
        float dv = rsqrtf((float)degi[i] + 1.0f);  // +1 = self loop
        dinv[i] = dv;
        xs[i * 3 + 0] = dv * x[i * 3 + 0];
        xs[i * 3 + 1] = dv * x[i * 3 + 1];
        xs[i * 3 + 2] = dv * x[i * 3 + 2];
    }
    if (i == 0) rowptr[N] = N_EDGES;
    // folded weight cast+transpose (40960 items over 50176 threads)
    if (i < 64 * 128) {                       // Wt2: [f=128][k=64]
        int f = i / 64, k = i % 64;
        Wt2[i] = bf16_rne(W2[k * 128 + f]);
    } else if (i < 64 * 128 + 128 * 256) {    // Wt3: [f=256][k=128]
        int j = i - 64 * 128;
        int f = j / 128, k = j % 128;
        Wt3[j] = bf16_rne(W3[k * 256 + f]);
    }
}

// ---- CSR fill: no atomic (rank precomputed) --------------------------------
__global__ void k_fill(const int* __restrict__ row, const int* __restrict__ col,
                       const int* __restrict__ rowptr, const int* __restrict__ pos,
                       int* __restrict__ csr_src, int E) {
    int e = blockIdx.x * blockDim.x + threadIdx.x;
    if (e >= E) return;
    int c = col[e];
    csr_src[rowptr[c] + pos[e]] = row[e];
}

// ---- fused layer 1: p1 = dv*(xs[v]+Σxs[r]); h1' = dv*relu(p1 W1 + b1) ------
__global__ void k_layer1(const float* __restrict__ xs, const float* __restrict__ dinv,
                         const int* __restrict__ rowptr, const int* __restrict__ csr_src,
                         const float* __restrict__ W1, const float* __restrict__ b1,
                         unsigned short* __restrict__ out, int N) {
    int v = blockIdx.x * blockDim.x + threadIdx.x;
    if (v >= N) return;
    float a0 = xs[v * 3 + 0];
    float a1 = xs[v * 3 + 1];
    float a2 = xs[v * 3 + 2];
    int j1 = rowptr[v + 1];
    for (int j = rowptr[v]; j < j1; ++j) {
        int r = csr_src[j];
        a0 += xs[r * 3 + 0];
        a1 += xs[r * 3 + 1];
        a2 += xs[r * 3 + 2];
    }
    float dv = dinv[v];
    float p0 = dv * a0, p1 = dv * a1, p2 = dv * a2;
    unsigned short* ov = out + (long)v * 64;
#pragma unroll
    for (int f = 0; f < 64; f += 2) {
        float s0 = fmaf(p0, W1[f],     fmaf(p1, W1[64 + f],     fmaf(p2, W1[128 + f],     b1[f])));
        float s1 = fmaf(p0, W1[f + 1], fmaf(p1, W1[64 + f + 1], fmaf(p2, W1[128 + f + 1], b1[f + 1])));
        s0 = fmaxf(s0, 0.0f) * dv;  // pre-scale for next prop
        s1 = fmaxf(s1, 0.0f) * dv;
        unsigned pk = (unsigned)bf16_rne(s0) | ((unsigned)bf16_rne(s1) << 16);
        *(unsigned*)(ov + f) = pk;
    }
}

// ---- FUSED prop + MFMA GEMM per 16-row m-tile ------------------------------
// Block = 256 thr = 4 waves = one m-tile (N = 3125*16, no tail).
// Phase 1: wave w gathers rows m0+4w..+3 (pure adds, pre-scaled input; same
//   summation order as old k_propb -> bit-identical), rounds dv*acc to bf16
//   into LDS tile [16][K+8] (pad 8 shorts: write banks lane%32 free; read
//   b128 A-frags spread across all banks at 272/144 B row stride).
// Phase 2: verified R9/R11 MFMA layout, A-frags from LDS (loaded once, reused
//   over FPW f-tiles), B-frags from L2-hot Wt.
template <int K, int F, bool PRESCALE>
__global__ __launch_bounds__(256) void k_fused(
        const unsigned short* __restrict__ h, const float* __restrict__ dinv,
        const int* __restrict__ rowptr, const int* __restrict__ csr_src,
        const unsigned short* __restrict__ Wt, const float* __restrict__ b,
        unsigned short* __restrict__ out, int N) {
    constexpr int NF = F / 16;    // f-tiles: 8 (F=128) / 16 (F=256)
    constexpr int FPW = NF / 4;   // f-tiles per wave: 2 / 4
    constexpr int KB = K / 32;    // k-blocks: 2 / 4
    constexpr int KL = K / 64;    // features per lane in prop: 1 / 2
    constexpr int PADK = K + 8;
    __shared__ unsigned short plds[16][PADK];
    int wave = threadIdx.x >> 6;
    int lane = threadIdx.x & 63;
    int m0 = blockIdx.x * 16;

    // ---- phase 1: propagation into LDS ----
    for (int rr = 0; rr < 4; ++rr) {
        int v = m0 + wave * 4 + rr;
        float acc[KL];
        const unsigned short* hv = h + (long)v * K + lane * KL;
        if (KL == 2) {
            unsigned u = *(const unsigned*)hv;
            acc[0] = __uint_as_float(u << 16);
            acc[1] = __uint_as_float(u & 0xFFFF0000u);
        } else {
            acc[0] = bfl(hv[0]);
        }
        int j0 = __builtin_amdgcn_readfirstlane(rowptr[v]);
        int j1 = __builtin_amdgcn_readfirstlane(rowptr[v + 1]);
        int j = j0;
        for (; j + 8 <= j1; j += 8) {
            int r[8];
#pragma unroll
            for (int u = 0; u < 8; ++u) r[u] = csr_src[j + u];
            if (KL == 2) {
                unsigned tv[8];
#pragma unroll
                for (int u = 0; u < 8; ++u)
                    tv[u] = *(const unsigned*)(h + (long)r[u] * K + lane * 2);
#pragma unroll
                for (int u = 0; u < 8; ++u) {
                    acc[0] += __uint_as_float(tv[u] << 16);
                    acc[1] += __uint_as_float(tv[u] & 0xFFFF0000u);
                }
            } else {
                unsigned short tv[8];
#pragma unroll
                for (int u = 0; u < 8; ++u) tv[u] = h[(long)r[u] * K + lane];
#pragma unroll
                for (int u = 0; u < 8; ++u) acc[0] += bfl(tv[u]);
            }
        }
        for (; j < j1; ++j) {
            int r = csr_src[j];
            if (KL == 2) {
                unsigned u = *(const unsigned*)(h + (long)r * K + lane * 2);
                acc[0] += __uint_as_float(u << 16);
                acc[1] += __uint_as_float(u & 0xFFFF0000u);
            } else {
                acc[0] += bfl(h[(long)r * K + lane]);
            }
        }
        float dv = dinv[v];
        int rloc = wave * 4 + rr;
        if (KL == 2) {
            unsigned pk = (unsigned)bf16_rne(dv * acc[0])
                        | ((unsigned)bf16_rne(dv * acc[1]) << 16);
            *(unsigned*)&plds[rloc][lane * 2] = pk;
        } else {
            plds[rloc][lane] = bf16_rne(dv * acc[0]);
        }
    }
    __syncthreads();

    // ---- phase 2: MFMA (layout verified R9/R11) ----
    int quad = lane >> 4;
    int l16 = lane & 15;
    bf16x8 afr[KB];
#pragma unroll
    for (int kb = 0; kb < KB; ++kb)
        afr[kb] = *(const bf16x8*)(const void*)&plds[l16][kb * 32 + quad * 8];
#pragma unroll
    for (int fi = 0; fi < FPW; ++fi) {
        int f0 = (wave * FPW + fi) * 16;
        const unsigned short* wrow = Wt + (long)(f0 + l16) * K + quad * 8;
        f32x4 acc4 = {0.f, 0.f, 0.f, 0.f};
#pragma unroll
        for (int kb = 0; kb < KB; ++kb) {
            bf16x8 bb = *(const bf16x8*)(const void*)(wrow + kb * 32);
            acc4 = __builtin_amdgcn_mfma_f32_16x16x32_bf16(afr[kb], bb, acc4, 0, 0, 0);
        }
        float bias = b[f0 + l16];
#pragma unroll
        for (int r = 0; r < 4; ++r) {
            int m = m0 + quad * 4 + r;
            float val = fmaxf(acc4[r] + bias, 0.0f);
            if (PRESCALE) val *= dinv[m];
            out[(long)m * F + f0 + l16] = bf16_rne(val);
        }
    }
}

// ---- pooling over bf16 h3: 64 nodes/block, register acc, flush on change ---
#define POOL_CHUNK 64
__global__ __launch_bounds__(256) void k_pool(
        const unsigned short* __restrict__ h, const int* __restrict__ batch,
        float* __restrict__ psum, int N) {
    int tid = threadIdx.x;  // feature
    int n0 = blockIdx.x * POOL_CHUNK;
    int n1 = n0 + POOL_CHUNK;
    if (n1 > N) n1 = N;
    int gcur = batch[n0];  // sorted -> uniform scalar
    float racc = 0.0f;
    for (int n = n0; n < n1; ++n) {
        int g = batch[n];
        if (g != gcur) {
            atomicAdd(&psum[gcur * 256 + tid], racc);
            racc = 0.0f;
            gcur = g;
        }
        racc += bfl(h[(long)n * 256 + tid]);
    }
    atomicAdd(&psum[gcur * 256 + tid], racc);
}

// ---- final FC --------------------------------------------------------------
__global__ void k_fc(const float* __restrict__ psum, const float* __restrict__ pcnt,
                     const float* __restrict__ Wfc, const float* __restrict__ bfc,
                     float* __restrict__ out) {
    int tid = blockIdx.x * blockDim.x + threadIdx.x;
    if (tid >= NUM_GRAPHS * NUM_CLASSES) return;
    int g = tid / NUM_CLASSES;
    int c = tid % NUM_CLASSES;
    float s = 0.0f;
#pragma unroll 8
    for (int k = 0; k < 256; ++k) s = fmaf(psum[g * 256 + k], Wfc[k * NUM_CLASSES + c], s);
    float cnt = pcnt[g];
    cnt = cnt > 1.0f ? cnt : 1.0f;
    out[tid] = s / cnt + bfc[c];
}

extern "C" void kernel_launch(void* const* d_in, const int* in_sizes, int n_in,
                              void* d_out, int out_size, void* d_ws, size_t ws_size,
                              hipStream_t stream) {
    const float* x     = (const float*)d_in[0];
    const int*   ei    = (const int*)d_in[1];
    const int*   batch = (const int*)d_in[2];
    const float* W1    = (const float*)d_in[3];
    const float* b1    = (const float*)d_in[4];
    const float* W2    = (const float*)d_in[5];
    const float* b2    = (const float*)d_in[6];
    const float* W3    = (const float*)d_in[7];
    const float* b3    = (const float*)d_in[8];
    const float* Wfc   = (const float*)d_in[9];
    const float* bfc   = (const float*)d_in[10];
    float* out = (float*)d_out;

    const int* row = ei;            // src
    const int* col = ei + N_EDGES;  // dst

    // workspace layout (~85 MB), bf16 arrays 16B-aligned
    float*  bufA = (float*)d_ws;                         // N*256 f32 (H3 bf16 lives here)
    float*  xs   = bufA + (size_t)N_NODES * 256;         // N*3 f32 (pre-scaled x)
    float*  dinv = xs + (size_t)N_NODES * 3;             // N
    float*  psum = dinv + N_NODES;                       // 16*256
    float*  pcnt = psum + NUM_GRAPHS * 256;              // 16
    unsigned short* X   = (unsigned short*)(pcnt + NUM_GRAPHS);  // N*128 bf16 (h1')
    unsigned short* Y   = X + (size_t)N_NODES * 128;             // N*128 bf16 (h2')
    unsigned short* Wt2 = Y + (size_t)N_NODES * 128;             // 128*64
    unsigned short* Wt3 = Wt2 + 128 * 64;                        // 256*128
    unsigned short* H3  = (unsigned short*)bufA;                 // N*256 bf16
    int* degi   = (int*)(Wt3 + 256 * 128);               // N
    int* rowptr = degi + N_NODES;                        // N+1
    int* csrsrc = rowptr + N_NODES + 1;                  // E
    int* pos    = csrsrc + N_EDGES;                      // E
    int* bsum   = pos + N_EDGES;                         // SCAN_BLOCKS

    hipMemsetAsync(degi, 0, N_NODES * sizeof(int), stream);
    hipMemsetAsync(psum, 0, (NUM_GRAPHS * 256 + NUM_GRAPHS) * sizeof(float), stream);

    // ---- CSR build + norms + pre-scaled x + weight casts ----
    k_deg<<<nblk(N_EDGES), 256, 0, stream>>>(col, degi, pos, N_EDGES);
    k_scan1<<<SCAN_BLOCKS, 256, 0, stream>>>(degi, rowptr, bsum, batch, pcnt, N_NODES);
    k_scan3<<<SCAN_BLOCKS, 256, 0, stream>>>(rowptr, bsum, degi, dinv, x, xs,
                                             W2, W3, Wt2, Wt3, N_NODES);
    k_fill<<<nblk(N_EDGES), 256, 0, stream>>>(row, col, rowptr, pos, csrsrc, N_EDGES);

    // ---- layer 1 (fused prop+linear): X = h1' = d*relu((A~x)W1+b1), bf16 ---
    k_layer1<<<nblk(N_NODES), 256, 0, stream>>>(xs, dinv, rowptr, csrsrc, W1, b1, X, N_NODES);

    int mtiles = N_NODES / 16;  // 3125, exact

    // ---- layer 2 fused: Y = h2' = d*relu((A~-apply X) W2 + b2) -------------
    k_fused<64, 128, true><<<mtiles, 256, 0, stream>>>(X, dinv, rowptr, csrsrc,
                                                       Wt2, b2, Y, N_NODES);

    // ---- layer 3 fused: H3 = h3 = relu((A~-apply Y) W3 + b3) (unscaled) ----
    k_fused<128, 256, false><<<mtiles, 256, 0, stream>>>(Y, dinv, rowptr, csrsrc,
                                                         Wt3, b3, H3, N_NODES);

    // ---- global mean pool + FC ----
    int pool_blocks = (N_NODES + POOL_CHUNK - 1) / POOL_CHUNK;
    k_pool<<<pool_blocks, 256, 0, stream>>>(H3, batch, psum, N_NODES);
    k_fc<<<nblk(NUM_GRAPHS * NUM_CLASSES), 256, 0, stream>>>(psum, pcnt, Wfc, bfc, out);
}